// Round 11
// baseline (2710.878 us; speedup 1.0000x reference)
//
#include <hip/hip_runtime.h>

#define DI __device__ __forceinline__

typedef __attribute__((ext_vector_type(8))) __bf16 bf16x8;
typedef __attribute__((ext_vector_type(4))) float f32x4;
typedef __attribute__((ext_vector_type(4))) unsigned int u32x4;
typedef __attribute__((ext_vector_type(4))) unsigned short u16x4;

// Problem constants
static constexpr int Bc = 4, Tc = 1024, Dc = 1024, Hc = 16, HSc = 64, HIDc = 4096, Lc = 4;

DI unsigned short f2bf(float f) {
    union { float f; unsigned int u; } c; c.f = f;
    unsigned int u = c.u;
    u += 0x7fffu + ((u >> 16) & 1u);   // RNE
    return (unsigned short)(u >> 16);
}
DI float bf2f(unsigned short h) {
    union { unsigned int u; float f; } c; c.u = ((unsigned int)h) << 16;
    return c.f;
}

DI void gload_lds16(const void* g, void* l) {
    __builtin_amdgcn_global_load_lds((const __attribute__((address_space(1))) void*)g,
                                     (__attribute__((address_space(3))) void*)l, 16, 0, 0);
}

DI f32x4 mfma16x16x32(bf16x8 a, bf16x8 b, f32x4 c) {
    return __builtin_amdgcn_mfma_f32_16x16x32_bf16(a, b, c, 0, 0, 0);
}

// ---------------- weight transpose + f32->bf16 cast: W[l][K][N] -> Wt[l][rowOff+N][K] ----------------
__global__ __launch_bounds__(256) void transpose_cast_kernel(const float* __restrict__ W,
                                                             unsigned short* __restrict__ Wt,
                                                             int K, int N, size_t lstride, int rowOff) {
    __shared__ float tile[32][33];
    const int l = blockIdx.z;
    const float* Wl = W + (size_t)l * K * N;
    unsigned short* Wtl = Wt + (size_t)l * lstride;
    const int n0 = blockIdx.x * 32, k0 = blockIdx.y * 32;
    const int tx = threadIdx.x, ty = threadIdx.y;
#pragma unroll
    for (int i = 0; i < 32; i += 8) tile[ty + i][tx] = Wl[(size_t)(k0 + ty + i) * N + (n0 + tx)];
    __syncthreads();
#pragma unroll
    for (int i = 0; i < 32; i += 8)
        Wtl[(size_t)(rowOff + n0 + ty + i) * K + (k0 + tx)] = f2bf(tile[tx][ty + i]);
}

// ---------------- f32 copy (x -> residual in d_out) ----------------
__global__ __launch_bounds__(256) void copy_f32_kernel(const float* __restrict__ in,
                                                       float* __restrict__ out, int n4) {
    const int i = blockIdx.x * 256 + threadIdx.x;
    if (i < n4) ((f32x4*)out)[i] = ((const f32x4*)in)[i];
}

// ---------------- residual reduce: xres += sum of NZ split-K partials ----------------
template <int NZ>
__global__ __launch_bounds__(256) void reduce_resN_kernel(const float* __restrict__ psum,
                                                          size_t zstr4,
                                                          float* __restrict__ xres, int n4) {
    const int i = blockIdx.x * 256 + threadIdx.x;
    if (i < n4) {
        f32x4 r = ((f32x4*)xres)[i];
#pragma unroll
        for (int z = 0; z < NZ; ++z) {
            const f32x4 a = ((const f32x4*)psum)[z * zstr4 + i];
            r[0] += a[0]; r[1] += a[1]; r[2] += a[2]; r[3] += a[3];
        }
        ((f32x4*)xres)[i] = r;
    }
}

// ---------------- RoPE sin/cos table [T][32] ----------------
__global__ __launch_bounds__(256) void rope_table_kernel(float* __restrict__ cosT,
                                                         float* __restrict__ sinT) {
    const int idx = blockIdx.x * 256 + threadIdx.x;  // T*32 = 32768
    const int t = idx >> 5, j = idx & 31;
    const float ts = powf(10000.f, (float)(2 * j) * (1.f / 64.f));
    const float ang = (float)t / ts;
    sinT[idx] = sinf(ang);
    cosT[idx] = cosf(ang);
}

// ---------------- RMSNorm over D=1024: f32 in -> bf16 out ----------------
__global__ __launch_bounds__(256) void rmsnorm_kernel(const float* __restrict__ x,
                                                      const float* __restrict__ scale,
                                                      unsigned short* __restrict__ out) {
    const int row = blockIdx.x;
    const int tid = threadIdx.x;
    const f32x4 v = ((const f32x4*)(x + (size_t)row * Dc))[tid];
    float ss = v[0] * v[0] + v[1] * v[1] + v[2] * v[2] + v[3] * v[3];
#pragma unroll
    for (int m = 32; m; m >>= 1) ss += __shfl_xor(ss, m);
    __shared__ float red[4];
    if ((tid & 63) == 0) red[tid >> 6] = ss;
    __syncthreads();
    const float tot = red[0] + red[1] + red[2] + red[3];
    const float r = rsqrtf(tot * (1.f / (float)Dc) + 1e-6f);
    const f32x4 sc = ((const f32x4*)scale)[tid];
    u16x4 o;
    o[0] = f2bf(v[0] * r * sc[0]);
    o[1] = f2bf(v[1] * r * sc[1]);
    o[2] = f2bf(v[2] * r * sc[2]);
    o[3] = f2bf(v[3] * r * sc[3]);
    *((u16x4*)(out + (size_t)row * Dc) + tid) = o;
}

// ---------------- RMSNorm + fold NZ split-K partials into xres, then norm ----------------
template <int NZ>
__global__ __launch_bounds__(256) void rmsnorm_addN_kernel(float* __restrict__ xres,
                                                           const float* __restrict__ psum,
                                                           size_t zstr4,
                                                           const float* __restrict__ scale,
                                                           unsigned short* __restrict__ out) {
    const int row = blockIdx.x;
    const int tid = threadIdx.x;
    const size_t i = (size_t)row * (Dc / 4) + tid;
    f32x4 v = ((const f32x4*)xres)[i];
#pragma unroll
    for (int z = 0; z < NZ; ++z) {
        const f32x4 a = ((const f32x4*)psum)[z * zstr4 + i];
        v[0] += a[0]; v[1] += a[1]; v[2] += a[2]; v[3] += a[3];
    }
    ((f32x4*)xres)[i] = v;
    float ss = v[0] * v[0] + v[1] * v[1] + v[2] * v[2] + v[3] * v[3];
#pragma unroll
    for (int m = 32; m; m >>= 1) ss += __shfl_xor(ss, m);
    __shared__ float red[4];
    if ((tid & 63) == 0) red[tid >> 6] = ss;
    __syncthreads();
    const float tot = red[0] + red[1] + red[2] + red[3];
    const float r = rsqrtf(tot * (1.f / (float)Dc) + 1e-6f);
    const f32x4 sc = ((const f32x4*)scale)[tid];
    u16x4 o;
    o[0] = f2bf(v[0] * r * sc[0]);
    o[1] = f2bf(v[1] * r * sc[1]);
    o[2] = f2bf(v[2] * r * sc[2]);
    o[3] = f2bf(v[3] * r * sc[3]);
    *((u16x4*)(out + (size_t)row * Dc) + tid) = o;
}

// ---------------- per-(b,t,h) RMSNorm over HS=64 + RoPE, in-place on bf16 (vectorized) ----------------
// blockIdx.y: 0 -> q, 1 -> k (merged dispatch)
__global__ __launch_bounds__(256) void qk_rope_kernel(unsigned short* __restrict__ q,
                                                      unsigned short* __restrict__ k,
                                                      const float* __restrict__ qscale,
                                                      const float* __restrict__ kscale,
                                                      const float* __restrict__ cosT,
                                                      const float* __restrict__ sinT) {
    unsigned short* buf = blockIdx.y ? k : q;
    const float* scl = blockIdx.y ? kscale : qscale;
    const int tid = threadIdx.x;
    const int sub = tid & 7;
    const size_t row = (size_t)blockIdx.x * 32 + (tid >> 3);   // index into [B*T*H]
    const int t = (int)((row >> 4) & (size_t)(Tc - 1));
    unsigned short* qr = buf + row * 64;
    const u32x4 pk = *(const u32x4*)(qr + sub * 8);
    float v[8];
#pragma unroll
    for (int i = 0; i < 4; ++i) {
        v[2 * i] = bf2f((unsigned short)(pk[i] & 0xffffu));
        v[2 * i + 1] = bf2f((unsigned short)(pk[i] >> 16));
    }
    float ss = 0.f;
#pragma unroll
    for (int i = 0; i < 8; ++i) ss += v[i] * v[i];
    ss += __shfl_xor(ss, 1, 8);
    ss += __shfl_xor(ss, 2, 8);
    ss += __shfl_xor(ss, 4, 8);
    const float rn = rsqrtf(ss * (1.f / 64.f) + 1e-6f);
    const f32x4 sc0 = ((const f32x4*)scl)[sub * 2];
    const f32x4 sc1 = ((const f32x4*)scl)[sub * 2 + 1];
    float xn[8];
#pragma unroll
    for (int i = 0; i < 8; ++i) xn[i] = v[i] * rn * (i < 4 ? sc0[i] : sc1[i - 4]);
    float other[8];
#pragma unroll
    for (int i = 0; i < 8; ++i) other[i] = __shfl_xor(xn[i], 4, 8);
    const int jb = (sub & 3) * 8;
    const f32x4 c0 = *(const f32x4*)(cosT + t * 32 + jb);
    const f32x4 c1 = *(const f32x4*)(cosT + t * 32 + jb + 4);
    const f32x4 s0 = *(const f32x4*)(sinT + t * 32 + jb);
    const f32x4 s1 = *(const f32x4*)(sinT + t * 32 + jb + 4);
    u32x4 o;
#pragma unroll
    for (int i = 0; i < 4; ++i) {
        const float ca = (2 * i < 4) ? c0[2 * i] : c1[2 * i - 4];
        const float cb = (2 * i + 1 < 4) ? c0[2 * i + 1] : c1[2 * i - 3];
        const float sa = (2 * i < 4) ? s0[2 * i] : s1[2 * i - 4];
        const float sb = (2 * i + 1 < 4) ? s0[2 * i + 1] : s1[2 * i - 3];
        float oa, ob;
        if (sub < 4) { oa = xn[2 * i] * ca - other[2 * i] * sa; ob = xn[2 * i + 1] * cb - other[2 * i + 1] * sb; }
        else         { oa = xn[2 * i] * ca + other[2 * i] * sa; ob = xn[2 * i + 1] * cb + other[2 * i + 1] * sb; }
        o[i] = (unsigned int)f2bf(oa) | ((unsigned int)f2bf(ob) << 16);
    }
    *(u32x4*)(qr + sub * 8) = o;
}

// ---------------- V transpose: [B,T,H,64] -> [B,H,64,T] (bf16) ----------------
__global__ __launch_bounds__(256) void vtrans_kernel(const unsigned short* __restrict__ v,
                                                     unsigned short* __restrict__ vt) {
    __shared__ unsigned short tile[32][33];
    const int bh = blockIdx.z, b = bh >> 4, h = bh & 15;
    const int t0 = blockIdx.x * 32, d0 = blockIdx.y * 32;
    const int tx = threadIdx.x, ty = threadIdx.y;
#pragma unroll
    for (int i = 0; i < 32; i += 8)
        tile[ty + i][tx] = v[(((size_t)b * Tc + (t0 + ty + i)) * Hc + h) * 64 + (d0 + tx)];
    __syncthreads();
#pragma unroll
    for (int i = 0; i < 32; i += 8)
        vt[(((size_t)b * Hc + h) * 64 + (d0 + ty + i)) * Tc + (t0 + tx)] = tile[tx][ty + i];
}

// ================= 128x128 m97-structure bf16 MFMA GEMM =================
// EPI 0: fused QKV (N=3072 -> 3x1024 outs), out = bf16(acc + bias)
// EPI 4: resout[kz*zstride + idx] = acc (+bias0 if kz==0)   [f32 partial, split-K]
template <int EPI>
__global__ __launch_bounds__(256, 4) void gemm_bt_kernel(
    const unsigned short* __restrict__ A, const unsigned short* __restrict__ Bt,
    const float* __restrict__ bias0, const float* __restrict__ bias1, const float* __restrict__ bias2,
    unsigned short* __restrict__ out0, unsigned short* __restrict__ out1, unsigned short* __restrict__ out2,
    float* __restrict__ resout,
    int N, int K, int KZ, size_t zstride, int nbn) {
    __shared__ unsigned short As[128 * 64];
    __shared__ unsigned short Bs[128 * 64];
    const int tid = threadIdx.x, w = tid >> 6, l = tid & 63;
    const int wr = w >> 1, wc = w & 1;
    const int nwg = gridDim.x;
    const int t = (blockIdx.x & 7) * (nwg >> 3) + (blockIdx.x >> 3);
    const int st = t >> 6, r = t & 63;
    const int nsn = nbn >> 3;
    const int sm = st / nsn, sn = st - sm * nsn;
    const int bm = sm * 8 + (r >> 3), bn = sn * 8 + (r & 7);
    const int kz = blockIdx.z;

    const unsigned short* Ag = A + (size_t)bm * 128 * K + (size_t)kz * KZ;
    const unsigned short* Bg = Bt + (size_t)bn * 128 * K + (size_t)kz * KZ;
    const int nk = KZ >> 6;
    const int srow = (l >> 3);
    const int slc = (l & 7);

    f32x4 acc[4][4] = {};
    for (int kt = 0; kt < nk; ++kt) {
#pragma unroll
        for (int p = 0; p < 4; ++p) {
            const int row = w * 8 + p * 32 + srow;
            const int ce = slc ^ (row & 7);
            gload_lds16(Ag + (size_t)row * K + kt * 64 + ce * 8, &As[(w * 8 + p * 32) * 64]);
            gload_lds16(Bg + (size_t)row * K + kt * 64 + ce * 8, &Bs[(w * 8 + p * 32) * 64]);
        }
        __syncthreads();
        bf16x8 av[4][2], bv[4][2];
#pragma unroll
        for (int mf = 0; mf < 4; ++mf)
#pragma unroll
            for (int ks = 0; ks < 2; ++ks) {
                const int arow = wr * 64 + mf * 16 + (l & 15);
                av[mf][ks] = *(const bf16x8*)&As[arow * 64 + (((ks * 4 + (l >> 4)) ^ (arow & 7)) << 3)];
                const int brow = wc * 64 + mf * 16 + (l & 15);
                bv[mf][ks] = *(const bf16x8*)&Bs[brow * 64 + (((ks * 4 + (l >> 4)) ^ (brow & 7)) << 3)];
            }
#pragma unroll
        for (int mf = 0; mf < 4; ++mf)
#pragma unroll
            for (int nf = 0; nf < 4; ++nf)
#pragma unroll
                for (int ks = 0; ks < 2; ++ks)
                    acc[mf][nf] = mfma16x16x32(av[mf][ks], bv[nf][ks], acc[mf][nf]);
        __syncthreads();
    }

    // epilogue; C/D layout: col = lane&15, row = (lane>>4)*4 + reg
    const int r0 = bm * 128 + wr * 64 + ((l >> 4) << 2);
    if constexpr (EPI == 0) {
        const int sel = bn >> 3;
        const float* bias = sel == 0 ? bias0 : (sel == 1 ? bias1 : bias2);
        unsigned short* o = sel == 0 ? out0 : (sel == 1 ? out1 : out2);
        const int cb = (bn & 7) * 128 + wc * 64 + (l & 15);
#pragma unroll
        for (int nf = 0; nf < 4; ++nf) {
            const int col = cb + nf * 16;
            const float bvv = bias[col];
#pragma unroll
            for (int mf = 0; mf < 4; ++mf)
#pragma unroll
                for (int g = 0; g < 4; ++g)
                    o[(size_t)(r0 + mf * 16 + g) * 1024 + col] = f2bf(acc[mf][nf][g] + bvv);
        }
    } else {   // EPI == 4
        const int c0 = bn * 128 + wc * 64 + (l & 15);
        const size_t zoff = (size_t)kz * zstride;
#pragma unroll
        for (int nf = 0; nf < 4; ++nf) {
            const int col = c0 + nf * 16;
            const float bvv = (bias0 && kz == 0) ? bias0[col] : 0.f;
#pragma unroll
            for (int mf = 0; mf < 4; ++mf)
#pragma unroll
                for (int g = 0; g < 4; ++g) {
                    const size_t idx = (size_t)(r0 + mf * 16 + g) * N + col;
                    resout[zoff + idx] = acc[mf][nf][g] + bvv;
                }
        }
    }
}

// ================= fused MLP gate+up, wave-specialized =================
// 512 threads: waves 0-3 compute gate = A@Wg^T, waves 4-7 compute up = A@W1^T
// for the SAME 128x128 tile (shared A/G/U stage). gelu(G) handed to up-waves via LDS.
// launch_bounds(512,6): 3 blocks/CU (LDS 48KB x 3 = 144KB fits; VGPR 60 x 6 waves/EU fits).
__global__ __launch_bounds__(512, 6) void gemm_mlp_kernel(
    const unsigned short* __restrict__ A, const unsigned short* __restrict__ Bg_,
    const unsigned short* __restrict__ Bu_, unsigned short* __restrict__ out,
    int N, int K, int nbn) {
    __shared__ unsigned short lds[3 * 128 * 64];   // As|Gs|Us; reused as P[128][132] in epilogue
    unsigned short* As = lds;
    unsigned short* Gs = lds + 128 * 64;
    unsigned short* Us = lds + 2 * 128 * 64;
    const int tid = threadIdx.x, w = tid >> 6, l = tid & 63;
    const int isUp = w >> 2;
    const int wq = w & 3;
    const int wr = wq >> 1, wc = wq & 1;
    const int nwg = gridDim.x;
    const int t = (blockIdx.x & 7) * (nwg >> 3) + (blockIdx.x >> 3);
    const int st = t >> 6, r = t & 63;
    const int nsn = nbn >> 3;
    const int sm = st / nsn, sn = st - sm * nsn;
    const int bm = sm * 8 + (r >> 3), bn = sn * 8 + (r & 7);

    const unsigned short* AgK = A + (size_t)bm * 128 * K;
    const unsigned short* GgK = Bg_ + (size_t)bn * 128 * K;
    const unsigned short* UgK = Bu_ + (size_t)bn * 128 * K;
    const unsigned short* Bs_my = isUp ? Us : Gs;
    const int nk = K >> 6;
    const int lr = l >> 3, slc = l & 7;

    f32x4 acc[4][4] = {};
    for (int kt = 0; kt < nk; ++kt) {
#pragma unroll
        for (int p = 0; p < 2; ++p) {
            const int rbase = p * 64 + w * 8;
            const int row = rbase + lr;
            const int ce = slc ^ (row & 7);
            gload_lds16(AgK + (size_t)row * K + kt * 64 + ce * 8, As + rbase * 64);
            gload_lds16(GgK + (size_t)row * K + kt * 64 + ce * 8, Gs + rbase * 64);
            gload_lds16(UgK + (size_t)row * K + kt * 64 + ce * 8, Us + rbase * 64);
        }
        __syncthreads();
#pragma unroll
        for (int ks = 0; ks < 2; ++ks) {
            bf16x8 av[4], bv[4];
#pragma unroll
            for (int mf = 0; mf < 4; ++mf) {
                const int arow = wr * 64 + mf * 16 + (l & 15);
                av[mf] = *(const bf16x8*)&As[arow * 64 + (((ks * 4 + (l >> 4)) ^ (arow & 7)) << 3)];
                const int brow = wc * 64 + mf * 16 + (l & 15);
                bv[mf] = *(const bf16x8*)&Bs_my[brow * 64 + (((ks * 4 + (l >> 4)) ^ (brow & 7)) << 3)];
            }
#pragma unroll
            for (int mf = 0; mf < 4; ++mf)
#pragma unroll
                for (int nf = 0; nf < 4; ++nf)
                    acc[mf][nf] = mfma16x16x32(av[mf], bv[nf], acc[mf][nf]);
        }
        __syncthreads();
    }

    // epilogue: gate waves write gelu(G) (bf16) to P; up waves multiply and store.
    unsigned short* P = lds;   // 128*132*2 = 33792 B, safe after last sync
    const int rl0 = wr * 64 + ((l >> 4) << 2);
    const int cl0 = wc * 64 + (l & 15);
    if (!isUp) {
#pragma unroll
        for (int nf = 0; nf < 4; ++nf)
#pragma unroll
            for (int mf = 0; mf < 4; ++mf)
#pragma unroll
                for (int g = 0; g < 4; ++g) {
                    const float gvl = acc[mf][nf][g];
                    const float z = 0.7978845608028654f * (gvl + 0.044715f * gvl * gvl * gvl);
                    P[(rl0 + mf * 16 + g) * 132 + cl0 + nf * 16] = f2bf(0.5f * gvl * (1.f + tanhf(z)));
                }
    }
    __syncthreads();
    if (isUp) {
        const int r0 = bm * 128 + rl0;
        const int c0 = bn * 128 + cl0;
#pragma unroll
        for (int nf = 0; nf < 4; ++nf)
#pragma unroll
            for (int mf = 0; mf < 4; ++mf)
#pragma unroll
                for (int g = 0; g < 4; ++g) {
                    const float p = bf2f(P[(rl0 + mf * 16 + g) * 132 + cl0 + nf * 16]);
                    out[(size_t)(r0 + mf * 16 + g) * N + (c0 + nf * 16)] = f2bf(p * acc[mf][nf][g]);
                }
    }
}

// ---------------- flash attention: q,k [B,T,H,64]; vt [B,H,64,T]; out [B,T,H,64] ----------------
// T14 async-STAGE split; launch_bounds(256,4) -> <=128 VGPR, up to 4 blocks/CU.
__global__ __launch_bounds__(256, 4) void attn_kernel(const unsigned short* __restrict__ q,
                                                      const unsigned short* __restrict__ k,
                                                      const unsigned short* __restrict__ vt,
                                                      unsigned short* __restrict__ o) {
    constexpr int ST = 72;
    __shared__ unsigned short Qs[64 * ST], Ks[64 * ST], Vs[64 * ST], Ps[64 * ST];
    const int qb = blockIdx.x, h = blockIdx.y, b = blockIdx.z;
    const int tid = threadIdx.x, wid = tid >> 6, lane = tid & 63;
    const size_t qkbase = ((size_t)b << 20) + ((size_t)h << 6);
    const size_t vbase = ((size_t)(b * 16 + h)) << 16;
#pragma unroll
    for (int p = 0; p < 2; ++p) {
        const int cid = tid + p * 256, r = cid >> 3, c = cid & 7;
        *(u32x4*)&Qs[r * ST + c * 8] =
            *(const u32x4*)&q[qkbase + (size_t)(qb * 64 + r) * 1024 + c * 8];
    }
    f32x4 oacc[4] = {};
    float mrun[4], lrun[4];
#pragma unroll
    for (int g = 0; g < 4; ++g) { mrun[g] = -1e30f; lrun[g] = 0.f; }
    const int fr = lane & 15, ko = (lane >> 4) * 8;
    u32x4 kr[2], vr[2];
#pragma unroll
    for (int p = 0; p < 2; ++p) {
        const int cid = tid + p * 256, r = cid >> 3, c = cid & 7;
        kr[p] = *(const u32x4*)&k[qkbase + (size_t)(r) * 1024 + c * 8];
        vr[p] = *(const u32x4*)&vt[vbase + (size_t)r * 1024 + c * 8];
    }
    for (int j = 0; j < 16; ++j) {
        __syncthreads();
#pragma unroll
        for (int p = 0; p < 2; ++p) {
            const int cid = tid + p * 256, r = cid >> 3, c = cid & 7;
            *(u32x4*)&Ks[r * ST + c * 8] = kr[p];
            *(u32x4*)&Vs[r * ST + c * 8] = vr[p];
        }
        __syncthreads();
        if (j < 15) {
#pragma unroll
            for (int p = 0; p < 2; ++p) {
                const int cid = tid + p * 256, r = cid >> 3, c = cid & 7;
                kr[p] = *(const u32x4*)&k[qkbase + (size_t)((j + 1) * 64 + r) * 1024 + c * 8];
                vr[p] = *(const u32x4*)&vt[vbase + (size_t)r * 1024 + (j + 1) * 64 + c * 8];
            }
        }
        f32x4 sacc[4] = {};
#pragma unroll
        for (int ks = 0; ks < 2; ++ks) {
            const bf16x8 a = *(const bf16x8*)&Qs[(wid * 16 + fr) * ST + ks * 32 + ko];
#pragma unroll
            for (int n = 0; n < 4; ++n) {
                const bf16x8 bb = *(const bf16x8*)&Ks[(n * 16 + fr) * ST + ks * 32 + ko];
                sacc[n] = mfma16x16x32(a, bb, sacc[n]);
            }
        }
        float s[4][4];
#pragma unroll
        for (int n = 0; n < 4; ++n)
#pragma unroll
            for (int g = 0; g < 4; ++g) s[n][g] = sacc[n][g] * 0.125f;
        float rmax[4];
#pragma unroll
        for (int g = 0; g < 4; ++g)
            rmax[g] = fmaxf(fmaxf(s[0][g], s[1][g]), fmaxf(s[2][g], s[3][g]));
#pragma unroll
        for (int msk = 1; msk < 16; msk <<= 1)
#pragma unroll
            for (int g = 0; g < 4; ++g) rmax[g] = fmaxf(rmax[g], __shfl_xor(rmax[g], msk));
        float mn[4], alpha[4], rsum[4];
#pragma unroll
        for (int g = 0; g < 4; ++g) {
            mn[g] = fmaxf(mrun[g], rmax[g]);
            alpha[g] = __expf(mrun[g] - mn[g]);
            mrun[g] = mn[g];
            rsum[g] = 0.f;
        }
#pragma unroll
        for (int n = 0; n < 4; ++n)
#pragma unroll
            for (int g = 0; g < 4; ++g) {
                const float p = __expf(s[n][g] - mn[g]);
                rsum[g] += p;
                Ps[(wid * 16 + (lane >> 4) * 4 + g) * ST + n * 16 + (lane & 15)] = f2bf(p);
            }
#pragma unroll
        for (int msk = 1; msk < 16; msk <<= 1)
#pragma unroll
            for (int g = 0; g < 4; ++g) rsum[g] += __shfl_xor(rsum[g], msk);
#pragma unroll
        for (int g = 0; g < 4; ++g) lrun[g] = lrun[g] * alpha[g] + rsum[g];
#pragma unroll
        for (int nd = 0; nd < 4; ++nd)
#pragma unroll
            for (int g = 0; g < 4; ++g) oacc[nd][g] *= alpha[g];
#pragma unroll
        for (int ks = 0; ks < 2; ++ks) {
            const bf16x8 a = *(const bf16x8*)&Ps[(wid * 16 + fr) * ST + ks * 32 + ko];
#pragma unroll
            for (int nd = 0; nd < 4; ++nd) {
                const bf16x8 bb = *(const bf16x8*)&Vs[(nd * 16 + fr) * ST + ks * 32 + ko];
                oacc[nd] = mfma16x16x32(a, bb, oacc[nd]);
            }
        }
    }
#pragma unroll
    for (int nd = 0; nd < 4; ++nd)
#pragma unroll
        for (int g = 0; g < 4; ++g) {
            const int r = qb * 64 + wid * 16 + (lane >> 4) * 4 + g;
            o[qkbase + (size_t)r * 1024 + nd * 16 + (lane & 15)] = f2bf(oacc[nd][g] / lrun[g]);
        }
}

extern "C" void kernel_launch(void* const* d_in, const int* in_sizes, int n_in,
                              void* d_out, int out_size, void* d_ws, size_t ws_size,
                              hipStream_t stream) {
    (void)in_sizes; (void)n_in; (void)out_size; (void)ws_size;
    const float* x   = (const float*)d_in[0];
    const float* Wq  = (const float*)d_in[2];
    const float* bq  = (const float*)d_in[3];
    const float* Wk  = (const float*)d_in[4];
    const float* bk  = (const float*)d_in[5];
    const float* Wv  = (const float*)d_in[6];
    const float* bv  = (const float*)d_in[7];
    const float* Wo  = (const float*)d_in[8];
    const float* bo  = (const float*)d_in[9];
    const float* qsc = (const float*)d_in[10];
    const float* ksc = (const float*)d_in[11];
    const float* ln1 = (const float*)d_in[12];
    const float* ln2 = (const float*)d_in[13];
    const float* Wg  = (const float*)d_in[14];
    const float* W1  = (const float*)d_in[15];
    const float* W2  = (const float*)d_in[16];
    float* xres = (float*)d_out;

    char* wsb = (char*)d_ws;
    size_t off = 0;
    auto alloc = [&](size_t bytes) -> char* {
        char* p = wsb + off;
        off += (bytes + 255) & ~(size_t)255;
        return p;
    };
    const size_t WQKV = (size_t)Lc * 3 * Dc * Dc;
    const size_t WPROJ = (size_t)Lc * Dc * Hc * HSc;
    const size_t WMLP  = (size_t)Lc * Dc * HIDc;
    unsigned short* wqkvT = (unsigned short*)alloc(WQKV * 2);
    unsigned short* woT = (unsigned short*)alloc(WPROJ * 2);
    unsigned short* wgT = (unsigned short*)alloc(WMLP * 2);
    unsigned short* w1T = (unsigned short*)alloc(WMLP * 2);
    unsigned short* w2T = (unsigned short*)alloc(WMLP * 2);
    float* ropeC = (float*)alloc((size_t)Tc * 32 * 4);
    float* ropeS = (float*)alloc((size_t)Tc * 32 * 4);
    unsigned short* xln  = (unsigned short*)alloc((size_t)Bc * Tc * Dc * 2);
    unsigned short* qbuf = (unsigned short*)alloc((size_t)Bc * Tc * Hc * HSc * 2);
    unsigned short* kbuf = (unsigned short*)alloc((size_t)Bc * Tc * Hc * HSc * 2);
    unsigned short* vbuf = (unsigned short*)alloc((size_t)Bc * Tc * Hc * HSc * 2);
    unsigned short* vtg  = (unsigned short*)alloc((size_t)Bc * Hc * HSc * Tc * 2);
    unsigned short* hbuf = (unsigned short*)alloc((size_t)Bc * Tc * HIDc * 2);
    float* psum = (float*)alloc((size_t)4 * Bc * Tc * Dc * 4);   // 4 split-K partials (64 MB)

    const dim3 b32(32, 8);
    const size_t qkvStride = (size_t)3 * Dc * Dc;
    transpose_cast_kernel<<<dim3(32, 32, 4), b32, 0, stream>>>(Wq, wqkvT, 1024, 1024, qkvStride, 0);
    transpose_cast_kernel<<<dim3(32, 32, 4), b32, 0, stream>>>(Wk, wqkvT, 1024, 1024, qkvStride, 1024);
    transpose_cast_kernel<<<dim3(32, 32, 4), b32, 0, stream>>>(Wv, wqkvT, 1024, 1024, qkvStride, 2048);
    transpose_cast_kernel<<<dim3(32, 32, 4), b32, 0, stream>>>(Wo, woT, 1024, 1024, (size_t)Dc * Dc, 0);
    transpose_cast_kernel<<<dim3(128, 32, 4), b32, 0, stream>>>(Wg, wgT, 1024, 4096, (size_t)Dc * HIDc, 0);
    transpose_cast_kernel<<<dim3(128, 32, 4), b32, 0, stream>>>(W1, w1T, 1024, 4096, (size_t)Dc * HIDc, 0);
    transpose_cast_kernel<<<dim3(32, 128, 4), b32, 0, stream>>>(W2, w2T, 4096, 1024, (size_t)Dc * HIDc, 0);
    rope_table_kernel<<<128, 256, 0, stream>>>(ropeC, ropeS);
    copy_f32_kernel<<<4096, 256, 0, stream>>>(x, xres, (Bc * Tc * Dc) / 4);

    const size_t zstr = (size_t)Bc * Tc * Dc;   // 4M f32 per partial
    for (int l = 0; l < Lc; ++l) {
        const unsigned short* wqkv_l = wqkvT + (size_t)l * qkvStride;
        const unsigned short* wo_l = woT + (size_t)l * Dc * Dc;
        const unsigned short* wg_l = wgT + (size_t)l * Dc * HIDc;
        const unsigned short* w1_l = w1T + (size_t)l * Dc * HIDc;
        const unsigned short* w2_l = w2T + (size_t)l * Dc * HIDc;

        if (l == 0)
            rmsnorm_kernel<<<4096, 256, 0, stream>>>(xres, ln1 + l * Dc, xln);
        else   // fold previous layer's 4 down-proj partials, then norm
            rmsnorm_addN_kernel<4><<<4096, 256, 0, stream>>>(xres, psum, zstr / 4, ln1 + l * Dc, xln);
        // fused QKV: M=4096, N=3072, K=1024 -> 768 blocks, 128^2
        gemm_bt_kernel<0><<<768, 256, 0, stream>>>(
            xln, wqkv_l, bq + l * 1024, bk + l * 1024, bv + l * 1024,
            qbuf, kbuf, vbuf, nullptr, 3072, 1024, 1024, 0, 24);
        // merged q+k rope (blockIdx.y selects buffer)
        qk_rope_kernel<<<dim3(2048, 2), 256, 0, stream>>>(qbuf, kbuf, qsc + l * 64, ksc + l * 64,
                                                          ropeC, ropeS);
        vtrans_kernel<<<dim3(32, 2, 64), b32, 0, stream>>>(vbuf, vtg);
        attn_kernel<<<dim3(16, 16, 4), 256, 0, stream>>>(qbuf, kbuf, vtg, xln);
        // Wo: split-K x2 -> f32 partials (bias on kz==0); 512 blocks
        gemm_bt_kernel<4><<<dim3(256, 1, 2), 256, 0, stream>>>(
            xln, wo_l, bo + l * 1024, nullptr, nullptr,
            nullptr, nullptr, nullptr, psum, 1024, 1024, 512, zstr, 8);
        // ln2: fold Wo partials into xres, then norm -> xln
        rmsnorm_addN_kernel<2><<<4096, 256, 0, stream>>>(xres, psum, zstr / 4, ln2 + l * Dc, xln);
        // fused MLP gate+up (wave-specialized, 3 blocks/CU): 1024 blocks x 512 thr
        gemm_mlp_kernel<<<1024, 512, 0, stream>>>(xln, wg_l, w1_l, hbuf, 4096, 1024, 32);
        // down: split-K x4 -> f32 partials (256 x 4 = 1024 blocks); folded next layer
        gemm_bt_kernel<4><<<dim3(256, 1, 4), 256, 0, stream>>>(
            hbuf, w2_l, nullptr, nullptr, nullptr,
            nullptr, nullptr, nullptr, psum, 1024, 4096, 1024, zstr, 8);
    }
    // finalize last layer's residual
    reduce_resN_kernel<4><<<4096, 256, 0, stream>>>(psum, zstr / 4, xres, (int)(zstr / 4));
}

// Round 12
// 1221.021 us; speedup vs baseline: 2.2202x; 2.2202x over previous
//
#include <hip/hip_runtime.h>

#define DI __device__ __forceinline__

typedef __attribute__((ext_vector_type(8))) __bf16 bf16x8;
typedef __attribute__((ext_vector_type(4))) float f32x4;
typedef __attribute__((ext_vector_type(4))) unsigned int u32x4;
typedef __attribute__((ext_vector_type(4))) unsigned short u16x4;

// Problem constants
static constexpr int Bc = 4, Tc = 1024, Dc = 1024, Hc = 16, HSc = 64, HIDc = 4096, Lc = 4;

DI unsigned short f2bf(float f) {
    union { float f; unsigned int u; } c; c.f = f;
    unsigned int u = c.u;
    u += 0x7fffu + ((u >> 16) & 1u);   // RNE
    return (unsigned short)(u >> 16);
}
DI float bf2f(unsigned short h) {
    union { unsigned int u; float f; } c; c.u = ((unsigned int)h) << 16;
    return c.f;
}

DI void gload_lds16(const void* g, void* l) {
    __builtin_amdgcn_global_load_lds((const __attribute__((address_space(1))) void*)g,
                                     (__attribute__((address_space(3))) void*)l, 16, 0, 0);
}

DI f32x4 mfma16x16x32(bf16x8 a, bf16x8 b, f32x4 c) {
    return __builtin_amdgcn_mfma_f32_16x16x32_bf16(a, b, c, 0, 0, 0);
}

// ---------------- weight transpose + f32->bf16 cast: W[l][K][N] -> Wt[l][rowOff+N][K] ----------------
__global__ __launch_bounds__(256) void transpose_cast_kernel(const float* __restrict__ W,
                                                             unsigned short* __restrict__ Wt,
                                                             int K, int N, size_t lstride, int rowOff) {
    __shared__ float tile[32][33];
    const int l = blockIdx.z;
    const float* Wl = W + (size_t)l * K * N;
    unsigned short* Wtl = Wt + (size_t)l * lstride;
    const int n0 = blockIdx.x * 32, k0 = blockIdx.y * 32;
    const int tx = threadIdx.x, ty = threadIdx.y;
#pragma unroll
    for (int i = 0; i < 32; i += 8) tile[ty + i][tx] = Wl[(size_t)(k0 + ty + i) * N + (n0 + tx)];
    __syncthreads();
#pragma unroll
    for (int i = 0; i < 32; i += 8)
        Wtl[(size_t)(rowOff + n0 + ty + i) * K + (k0 + tx)] = f2bf(tile[tx][ty + i]);
}

// ---------------- f32 copy (x -> residual in d_out) ----------------
__global__ __launch_bounds__(256) void copy_f32_kernel(const float* __restrict__ in,
                                                       float* __restrict__ out, int n4) {
    const int i = blockIdx.x * 256 + threadIdx.x;
    if (i < n4) ((f32x4*)out)[i] = ((const f32x4*)in)[i];
}

// ---------------- residual reduce: xres += p0 + p1 (split-K partials) ----------------
__global__ __launch_bounds__(256) void reduce_res_kernel(const float* __restrict__ p0,
                                                         const float* __restrict__ p1,
                                                         float* __restrict__ xres, int n4) {
    const int i = blockIdx.x * 256 + threadIdx.x;
    if (i < n4) {
        const f32x4 a = ((const f32x4*)p0)[i];
        const f32x4 b = ((const f32x4*)p1)[i];
        f32x4 r = ((f32x4*)xres)[i];
        r[0] += a[0] + b[0]; r[1] += a[1] + b[1]; r[2] += a[2] + b[2]; r[3] += a[3] + b[3];
        ((f32x4*)xres)[i] = r;
    }
}

// ---------------- RoPE sin/cos table [T][32] ----------------
__global__ __launch_bounds__(256) void rope_table_kernel(float* __restrict__ cosT,
                                                         float* __restrict__ sinT) {
    const int idx = blockIdx.x * 256 + threadIdx.x;  // T*32 = 32768
    const int t = idx >> 5, j = idx & 31;
    const float ts = powf(10000.f, (float)(2 * j) * (1.f / 64.f));
    const float ang = (float)t / ts;
    sinT[idx] = sinf(ang);
    cosT[idx] = cosf(ang);
}

// ---------------- RMSNorm over D=1024: f32 in -> bf16 out ----------------
__global__ __launch_bounds__(256) void rmsnorm_kernel(const float* __restrict__ x,
                                                      const float* __restrict__ scale,
                                                      unsigned short* __restrict__ out) {
    const int row = blockIdx.x;
    const int tid = threadIdx.x;
    const f32x4 v = ((const f32x4*)(x + (size_t)row * Dc))[tid];
    float ss = v[0] * v[0] + v[1] * v[1] + v[2] * v[2] + v[3] * v[3];
#pragma unroll
    for (int m = 32; m; m >>= 1) ss += __shfl_xor(ss, m);
    __shared__ float red[4];
    if ((tid & 63) == 0) red[tid >> 6] = ss;
    __syncthreads();
    const float tot = red[0] + red[1] + red[2] + red[3];
    const float r = rsqrtf(tot * (1.f / (float)Dc) + 1e-6f);
    const f32x4 sc = ((const f32x4*)scale)[tid];
    u16x4 o;
    o[0] = f2bf(v[0] * r * sc[0]);
    o[1] = f2bf(v[1] * r * sc[1]);
    o[2] = f2bf(v[2] * r * sc[2]);
    o[3] = f2bf(v[3] * r * sc[3]);
    *((u16x4*)(out + (size_t)row * Dc) + tid) = o;
}

// ---------------- RMSNorm + fold 2 split-K partials into xres, then norm ----------------
__global__ __launch_bounds__(256) void rmsnorm_add_kernel(float* __restrict__ xres,
                                                          const float* __restrict__ p0,
                                                          const float* __restrict__ p1,
                                                          const float* __restrict__ scale,
                                                          unsigned short* __restrict__ out) {
    const int row = blockIdx.x;
    const int tid = threadIdx.x;
    const size_t base = (size_t)row * Dc;
    f32x4 v = ((const f32x4*)(xres + base))[tid];
    const f32x4 a = ((const f32x4*)(p0 + base))[tid];
    const f32x4 b = ((const f32x4*)(p1 + base))[tid];
    v[0] += a[0] + b[0]; v[1] += a[1] + b[1]; v[2] += a[2] + b[2]; v[3] += a[3] + b[3];
    ((f32x4*)(xres + base))[tid] = v;
    float ss = v[0] * v[0] + v[1] * v[1] + v[2] * v[2] + v[3] * v[3];
#pragma unroll
    for (int m = 32; m; m >>= 1) ss += __shfl_xor(ss, m);
    __shared__ float red[4];
    if ((tid & 63) == 0) red[tid >> 6] = ss;
    __syncthreads();
    const float tot = red[0] + red[1] + red[2] + red[3];
    const float r = rsqrtf(tot * (1.f / (float)Dc) + 1e-6f);
    const f32x4 sc = ((const f32x4*)scale)[tid];
    u16x4 o;
    o[0] = f2bf(v[0] * r * sc[0]);
    o[1] = f2bf(v[1] * r * sc[1]);
    o[2] = f2bf(v[2] * r * sc[2]);
    o[3] = f2bf(v[3] * r * sc[3]);
    *((u16x4*)(out + (size_t)row * Dc) + tid) = o;
}

// ---------------- per-(b,t,h) RMSNorm over HS=64 + RoPE, in-place on bf16 (vectorized) ----------------
// blockIdx.y: 0 -> q, 1 -> k (merged dispatch)
__global__ __launch_bounds__(256) void qk_rope_kernel(unsigned short* __restrict__ q,
                                                      unsigned short* __restrict__ k,
                                                      const float* __restrict__ qscale,
                                                      const float* __restrict__ kscale,
                                                      const float* __restrict__ cosT,
                                                      const float* __restrict__ sinT) {
    unsigned short* buf = blockIdx.y ? k : q;
    const float* scl = blockIdx.y ? kscale : qscale;
    const int tid = threadIdx.x;
    const int sub = tid & 7;
    const size_t row = (size_t)blockIdx.x * 32 + (tid >> 3);   // index into [B*T*H]
    const int t = (int)((row >> 4) & (size_t)(Tc - 1));
    unsigned short* qr = buf + row * 64;
    const u32x4 pk = *(const u32x4*)(qr + sub * 8);
    float v[8];
#pragma unroll
    for (int i = 0; i < 4; ++i) {
        v[2 * i] = bf2f((unsigned short)(pk[i] & 0xffffu));
        v[2 * i + 1] = bf2f((unsigned short)(pk[i] >> 16));
    }
    float ss = 0.f;
#pragma unroll
    for (int i = 0; i < 8; ++i) ss += v[i] * v[i];
    ss += __shfl_xor(ss, 1, 8);
    ss += __shfl_xor(ss, 2, 8);
    ss += __shfl_xor(ss, 4, 8);
    const float rn = rsqrtf(ss * (1.f / 64.f) + 1e-6f);
    const f32x4 sc0 = ((const f32x4*)scl)[sub * 2];
    const f32x4 sc1 = ((const f32x4*)scl)[sub * 2 + 1];
    float xn[8];
#pragma unroll
    for (int i = 0; i < 8; ++i) xn[i] = v[i] * rn * (i < 4 ? sc0[i] : sc1[i - 4]);
    float other[8];
#pragma unroll
    for (int i = 0; i < 8; ++i) other[i] = __shfl_xor(xn[i], 4, 8);
    const int jb = (sub & 3) * 8;
    const f32x4 c0 = *(const f32x4*)(cosT + t * 32 + jb);
    const f32x4 c1 = *(const f32x4*)(cosT + t * 32 + jb + 4);
    const f32x4 s0 = *(const f32x4*)(sinT + t * 32 + jb);
    const f32x4 s1 = *(const f32x4*)(sinT + t * 32 + jb + 4);
    u32x4 o;
#pragma unroll
    for (int i = 0; i < 4; ++i) {
        const float ca = (2 * i < 4) ? c0[2 * i] : c1[2 * i - 4];
        const float cb = (2 * i + 1 < 4) ? c0[2 * i + 1] : c1[2 * i - 3];
        const float sa = (2 * i < 4) ? s0[2 * i] : s1[2 * i - 4];
        const float sb = (2 * i + 1 < 4) ? s0[2 * i + 1] : s1[2 * i - 3];
        float oa, ob;
        if (sub < 4) { oa = xn[2 * i] * ca - other[2 * i] * sa; ob = xn[2 * i + 1] * cb - other[2 * i + 1] * sb; }
        else         { oa = xn[2 * i] * ca + other[2 * i] * sa; ob = xn[2 * i + 1] * cb + other[2 * i + 1] * sb; }
        o[i] = (unsigned int)f2bf(oa) | ((unsigned int)f2bf(ob) << 16);
    }
    *(u32x4*)(qr + sub * 8) = o;
}

// ---------------- V transpose: [B,T,H,64] -> [B,H,64,T] (bf16) ----------------
__global__ __launch_bounds__(256) void vtrans_kernel(const unsigned short* __restrict__ v,
                                                     unsigned short* __restrict__ vt) {
    __shared__ unsigned short tile[32][33];
    const int bh = blockIdx.z, b = bh >> 4, h = bh & 15;
    const int t0 = blockIdx.x * 32, d0 = blockIdx.y * 32;
    const int tx = threadIdx.x, ty = threadIdx.y;
#pragma unroll
    for (int i = 0; i < 32; i += 8)
        tile[ty + i][tx] = v[(((size_t)b * Tc + (t0 + ty + i)) * Hc + h) * 64 + (d0 + tx)];
    __syncthreads();
#pragma unroll
    for (int i = 0; i < 32; i += 8)
        vt[(((size_t)b * Hc + h) * 64 + (d0 + ty + i)) * Tc + (t0 + tx)] = tile[tx][ty + i];
}

// ================= 128x128 m97-structure bf16 MFMA GEMM =================
// EPI 0: fused QKV (N=3072 -> 3x1024 outs), out = bf16(acc + bias)
// EPI 1: resout = resin + acc (+bias0 if non-null)   [f32, full-K only]
// EPI 4: resout[kz*zstride + idx] = acc               [f32 partial, split-K]
template <int EPI>
__global__ __launch_bounds__(256, 3) void gemm_bt_kernel(
    const unsigned short* __restrict__ A, const unsigned short* __restrict__ Bt,
    const float* __restrict__ bias0, const float* __restrict__ bias1, const float* __restrict__ bias2,
    unsigned short* __restrict__ out0, unsigned short* __restrict__ out1, unsigned short* __restrict__ out2,
    const float* __restrict__ resin, float* __restrict__ resout,
    int N, int K, int KZ, size_t zstride, int nbn) {
    __shared__ unsigned short As[128 * 64];
    __shared__ unsigned short Bs[128 * 64];
    const int tid = threadIdx.x, w = tid >> 6, l = tid & 63;
    const int wr = w >> 1, wc = w & 1;
    const int nwg = gridDim.x;
    const int t = (blockIdx.x & 7) * (nwg >> 3) + (blockIdx.x >> 3);
    const int st = t >> 6, r = t & 63;
    const int nsn = nbn >> 3;
    const int sm = st / nsn, sn = st - sm * nsn;
    const int bm = sm * 8 + (r >> 3), bn = sn * 8 + (r & 7);
    const int kz = blockIdx.z;

    const unsigned short* Ag = A + (size_t)bm * 128 * K + (size_t)kz * KZ;
    const unsigned short* Bg = Bt + (size_t)bn * 128 * K + (size_t)kz * KZ;
    const int nk = KZ >> 6;
    const int srow = (l >> 3);
    const int slc = (l & 7);

    f32x4 acc[4][4] = {};
    for (int kt = 0; kt < nk; ++kt) {
#pragma unroll
        for (int p = 0; p < 4; ++p) {
            const int row = w * 8 + p * 32 + srow;
            const int ce = slc ^ (row & 7);
            gload_lds16(Ag + (size_t)row * K + kt * 64 + ce * 8, &As[(w * 8 + p * 32) * 64]);
            gload_lds16(Bg + (size_t)row * K + kt * 64 + ce * 8, &Bs[(w * 8 + p * 32) * 64]);
        }
        __syncthreads();
        bf16x8 av[4][2], bv[4][2];
#pragma unroll
        for (int mf = 0; mf < 4; ++mf)
#pragma unroll
            for (int ks = 0; ks < 2; ++ks) {
                const int arow = wr * 64 + mf * 16 + (l & 15);
                av[mf][ks] = *(const bf16x8*)&As[arow * 64 + (((ks * 4 + (l >> 4)) ^ (arow & 7)) << 3)];
                const int brow = wc * 64 + mf * 16 + (l & 15);
                bv[mf][ks] = *(const bf16x8*)&Bs[brow * 64 + (((ks * 4 + (l >> 4)) ^ (brow & 7)) << 3)];
            }
#pragma unroll
        for (int mf = 0; mf < 4; ++mf)
#pragma unroll
            for (int nf = 0; nf < 4; ++nf)
#pragma unroll
                for (int ks = 0; ks < 2; ++ks)
                    acc[mf][nf] = mfma16x16x32(av[mf][ks], bv[nf][ks], acc[mf][nf]);
        __syncthreads();
    }

    // epilogue; C/D layout: col = lane&15, row = (lane>>4)*4 + reg
    const int r0 = bm * 128 + wr * 64 + ((l >> 4) << 2);
    if constexpr (EPI == 0) {
        const int sel = bn >> 3;
        const float* bias = sel == 0 ? bias0 : (sel == 1 ? bias1 : bias2);
        unsigned short* o = sel == 0 ? out0 : (sel == 1 ? out1 : out2);
        const int cb = (bn & 7) * 128 + wc * 64 + (l & 15);
#pragma unroll
        for (int nf = 0; nf < 4; ++nf) {
            const int col = cb + nf * 16;
            const float bvv = bias[col];
#pragma unroll
            for (int mf = 0; mf < 4; ++mf)
#pragma unroll
                for (int g = 0; g < 4; ++g)
                    o[(size_t)(r0 + mf * 16 + g) * 1024 + col] = f2bf(acc[mf][nf][g] + bvv);
        }
    } else {
        const int c0 = bn * 128 + wc * 64 + (l & 15);
        const size_t zoff = (size_t)kz * zstride;
#pragma unroll
        for (int nf = 0; nf < 4; ++nf) {
            const int col = c0 + nf * 16;
            float bvv = 0.f;
            if constexpr (EPI == 1) {
                if (bias0) bvv = bias0[col];
            }
#pragma unroll
            for (int mf = 0; mf < 4; ++mf)
#pragma unroll
                for (int g = 0; g < 4; ++g) {
                    const size_t idx = (size_t)(r0 + mf * 16 + g) * N + col;
                    const float val = acc[mf][nf][g];
                    if constexpr (EPI == 1) {
                        resout[idx] = resin[idx] + val + bvv;
                    } else {  // EPI == 4
                        resout[zoff + idx] = val;
                    }
                }
        }
    }
}

// ================= fused MLP gate+up, wave-specialized (proven best: (512,4), 2 blocks/CU) =================
// NOTE: (512,6) SPILLS — acc[4][4] = 64 AGPRs count against the unified VGPR/AGPR budget
// (total ~124 regs > 512/6 cap). Round-11 measured: 4x slowdown from scratch traffic. Keep (512,4).
__global__ __launch_bounds__(512, 4) void gemm_mlp_kernel(
    const unsigned short* __restrict__ A, const unsigned short* __restrict__ Bg_,
    const unsigned short* __restrict__ Bu_, unsigned short* __restrict__ out,
    int N, int K, int nbn) {
    __shared__ unsigned short lds[3 * 128 * 64];   // As|Gs|Us; reused as P[128][132] in epilogue
    unsigned short* As = lds;
    unsigned short* Gs = lds + 128 * 64;
    unsigned short* Us = lds + 2 * 128 * 64;
    const int tid = threadIdx.x, w = tid >> 6, l = tid & 63;
    const int isUp = w >> 2;
    const int wq = w & 3;
    const int wr = wq >> 1, wc = wq & 1;
    const int nwg = gridDim.x;
    const int t = (blockIdx.x & 7) * (nwg >> 3) + (blockIdx.x >> 3);
    const int st = t >> 6, r = t & 63;
    const int nsn = nbn >> 3;
    const int sm = st / nsn, sn = st - sm * nsn;
    const int bm = sm * 8 + (r >> 3), bn = sn * 8 + (r & 7);

    const unsigned short* AgK = A + (size_t)bm * 128 * K;
    const unsigned short* GgK = Bg_ + (size_t)bn * 128 * K;
    const unsigned short* UgK = Bu_ + (size_t)bn * 128 * K;
    const unsigned short* Bs_my = isUp ? Us : Gs;
    const int nk = K >> 6;
    const int lr = l >> 3, slc = l & 7;

    f32x4 acc[4][4] = {};
    for (int kt = 0; kt < nk; ++kt) {
#pragma unroll
        for (int p = 0; p < 2; ++p) {
            const int rbase = p * 64 + w * 8;
            const int row = rbase + lr;
            const int ce = slc ^ (row & 7);
            gload_lds16(AgK + (size_t)row * K + kt * 64 + ce * 8, As + rbase * 64);
            gload_lds16(GgK + (size_t)row * K + kt * 64 + ce * 8, Gs + rbase * 64);
            gload_lds16(UgK + (size_t)row * K + kt * 64 + ce * 8, Us + rbase * 64);
        }
        __syncthreads();
#pragma unroll
        for (int ks = 0; ks < 2; ++ks) {
            bf16x8 av[4], bv[4];
#pragma unroll
            for (int mf = 0; mf < 4; ++mf) {
                const int arow = wr * 64 + mf * 16 + (l & 15);
                av[mf] = *(const bf16x8*)&As[arow * 64 + (((ks * 4 + (l >> 4)) ^ (arow & 7)) << 3)];
                const int brow = wc * 64 + mf * 16 + (l & 15);
                bv[mf] = *(const bf16x8*)&Bs_my[brow * 64 + (((ks * 4 + (l >> 4)) ^ (brow & 7)) << 3)];
            }
#pragma unroll
            for (int mf = 0; mf < 4; ++mf)
#pragma unroll
                for (int nf = 0; nf < 4; ++nf)
                    acc[mf][nf] = mfma16x16x32(av[mf], bv[nf], acc[mf][nf]);
        }
        __syncthreads();
    }

    // epilogue: gate waves write gelu(G) (bf16) to P; up waves multiply and store.
    unsigned short* P = lds;   // 128*132*2 = 33792 B, safe after last sync
    const int rl0 = wr * 64 + ((l >> 4) << 2);
    const int cl0 = wc * 64 + (l & 15);
    if (!isUp) {
#pragma unroll
        for (int nf = 0; nf < 4; ++nf)
#pragma unroll
            for (int mf = 0; mf < 4; ++mf)
#pragma unroll
                for (int g = 0; g < 4; ++g) {
                    const float gvl = acc[mf][nf][g];
                    const float z = 0.7978845608028654f * (gvl + 0.044715f * gvl * gvl * gvl);
                    P[(rl0 + mf * 16 + g) * 132 + cl0 + nf * 16] = f2bf(0.5f * gvl * (1.f + tanhf(z)));
                }
    }
    __syncthreads();
    if (isUp) {
        const int r0 = bm * 128 + rl0;
        const int c0 = bn * 128 + cl0;
#pragma unroll
        for (int nf = 0; nf < 4; ++nf)
#pragma unroll
            for (int mf = 0; mf < 4; ++mf)
#pragma unroll
                for (int g = 0; g < 4; ++g) {
                    const float p = bf2f(P[(rl0 + mf * 16 + g) * 132 + cl0 + nf * 16]);
                    out[(size_t)(r0 + mf * 16 + g) * N + (c0 + nf * 16)] = f2bf(p * acc[mf][nf][g]);
                }
    }
}

// ---------------- flash attention: q,k [B,T,H,64]; vt [B,H,64,T]; out [B,T,H,64] ----------------
// T14 async-STAGE split: next K/V tile loaded into regs under current compute.
__global__ __launch_bounds__(256, 2) void attn_kernel(const unsigned short* __restrict__ q,
                                                      const unsigned short* __restrict__ k,
                                                      const unsigned short* __restrict__ vt,
                                                      unsigned short* __restrict__ o) {
    constexpr int ST = 72;
    __shared__ unsigned short Qs[64 * ST], Ks[64 * ST], Vs[64 * ST], Ps[64 * ST];
    const int qb = blockIdx.x, h = blockIdx.y, b = blockIdx.z;
    const int tid = threadIdx.x, wid = tid >> 6, lane = tid & 63;
    const size_t qkbase = ((size_t)b << 20) + ((size_t)h << 6);
    const size_t vbase = ((size_t)(b * 16 + h)) << 16;
#pragma unroll
    for (int p = 0; p < 2; ++p) {
        const int cid = tid + p * 256, r = cid >> 3, c = cid & 7;
        *(u32x4*)&Qs[r * ST + c * 8] =
            *(const u32x4*)&q[qkbase + (size_t)(qb * 64 + r) * 1024 + c * 8];
    }
    f32x4 oacc[4] = {};
    float mrun[4], lrun[4];
#pragma unroll
    for (int g = 0; g < 4; ++g) { mrun[g] = -1e30f; lrun[g] = 0.f; }
    const int fr = lane & 15, ko = (lane >> 4) * 8;
    u32x4 kr[2], vr[2];
#pragma unroll
    for (int p = 0; p < 2; ++p) {
        const int cid = tid + p * 256, r = cid >> 3, c = cid & 7;
        kr[p] = *(const u32x4*)&k[qkbase + (size_t)(r) * 1024 + c * 8];
        vr[p] = *(const u32x4*)&vt[vbase + (size_t)r * 1024 + c * 8];
    }
    for (int j = 0; j < 16; ++j) {
        __syncthreads();
#pragma unroll
        for (int p = 0; p < 2; ++p) {
            const int cid = tid + p * 256, r = cid >> 3, c = cid & 7;
            *(u32x4*)&Ks[r * ST + c * 8] = kr[p];
            *(u32x4*)&Vs[r * ST + c * 8] = vr[p];
        }
        __syncthreads();
        if (j < 15) {
#pragma unroll
            for (int p = 0; p < 2; ++p) {
                const int cid = tid + p * 256, r = cid >> 3, c = cid & 7;
                kr[p] = *(const u32x4*)&k[qkbase + (size_t)((j + 1) * 64 + r) * 1024 + c * 8];
                vr[p] = *(const u32x4*)&vt[vbase + (size_t)r * 1024 + (j + 1) * 64 + c * 8];
            }
        }
        f32x4 sacc[4] = {};
#pragma unroll
        for (int ks = 0; ks < 2; ++ks) {
            const bf16x8 a = *(const bf16x8*)&Qs[(wid * 16 + fr) * ST + ks * 32 + ko];
#pragma unroll
            for (int n = 0; n < 4; ++n) {
                const bf16x8 bb = *(const bf16x8*)&Ks[(n * 16 + fr) * ST + ks * 32 + ko];
                sacc[n] = mfma16x16x32(a, bb, sacc[n]);
            }
        }
        float s[4][4];
#pragma unroll
        for (int n = 0; n < 4; ++n)
#pragma unroll
            for (int g = 0; g < 4; ++g) s[n][g] = sacc[n][g] * 0.125f;
        float rmax[4];
#pragma unroll
        for (int g = 0; g < 4; ++g)
            rmax[g] = fmaxf(fmaxf(s[0][g], s[1][g]), fmaxf(s[2][g], s[3][g]));
#pragma unroll
        for (int msk = 1; msk < 16; msk <<= 1)
#pragma unroll
            for (int g = 0; g < 4; ++g) rmax[g] = fmaxf(rmax[g], __shfl_xor(rmax[g], msk));
        float mn[4], alpha[4], rsum[4];
#pragma unroll
        for (int g = 0; g < 4; ++g) {
            mn[g] = fmaxf(mrun[g], rmax[g]);
            alpha[g] = __expf(mrun[g] - mn[g]);
            mrun[g] = mn[g];
            rsum[g] = 0.f;
        }
#pragma unroll
        for (int n = 0; n < 4; ++n)
#pragma unroll
            for (int g = 0; g < 4; ++g) {
                const float p = __expf(s[n][g] - mn[g]);
                rsum[g] += p;
                Ps[(wid * 16 + (lane >> 4) * 4 + g) * ST + n * 16 + (lane & 15)] = f2bf(p);
            }
#pragma unroll
        for (int msk = 1; msk < 16; msk <<= 1)
#pragma unroll
            for (int g = 0; g < 4; ++g) rsum[g] += __shfl_xor(rsum[g], msk);
#pragma unroll
        for (int g = 0; g < 4; ++g) lrun[g] = lrun[g] * alpha[g] + rsum[g];
#pragma unroll
        for (int nd = 0; nd < 4; ++nd)
#pragma unroll
            for (int g = 0; g < 4; ++g) oacc[nd][g] *= alpha[g];
#pragma unroll
        for (int ks = 0; ks < 2; ++ks) {
            const bf16x8 a = *(const bf16x8*)&Ps[(wid * 16 + fr) * ST + ks * 32 + ko];
#pragma unroll
            for (int nd = 0; nd < 4; ++nd) {
                const bf16x8 bb = *(const bf16x8*)&Vs[(nd * 16 + fr) * ST + ks * 32 + ko];
                oacc[nd] = mfma16x16x32(a, bb, oacc[nd]);
            }
        }
    }
#pragma unroll
    for (int nd = 0; nd < 4; ++nd)
#pragma unroll
        for (int g = 0; g < 4; ++g) {
            const int r = qb * 64 + wid * 16 + (lane >> 4) * 4 + g;
            o[qkbase + (size_t)r * 1024 + nd * 16 + (lane & 15)] = f2bf(oacc[nd][g] / lrun[g]);
        }
}

extern "C" void kernel_launch(void* const* d_in, const int* in_sizes, int n_in,
                              void* d_out, int out_size, void* d_ws, size_t ws_size,
                              hipStream_t stream) {
    (void)in_sizes; (void)n_in; (void)out_size; (void)ws_size;
    const float* x   = (const float*)d_in[0];
    const float* Wq  = (const float*)d_in[2];
    const float* bq  = (const float*)d_in[3];
    const float* Wk  = (const float*)d_in[4];
    const float* bk  = (const float*)d_in[5];
    const float* Wv  = (const float*)d_in[6];
    const float* bv  = (const float*)d_in[7];
    const float* Wo  = (const float*)d_in[8];
    const float* bo  = (const float*)d_in[9];
    const float* qsc = (const float*)d_in[10];
    const float* ksc = (const float*)d_in[11];
    const float* ln1 = (const float*)d_in[12];
    const float* ln2 = (const float*)d_in[13];
    const float* Wg  = (const float*)d_in[14];
    const float* W1  = (const float*)d_in[15];
    const float* W2  = (const float*)d_in[16];
    float* xres = (float*)d_out;

    char* wsb = (char*)d_ws;
    size_t off = 0;
    auto alloc = [&](size_t bytes) -> char* {
        char* p = wsb + off;
        off += (bytes + 255) & ~(size_t)255;
        return p;
    };
    const size_t WQKV = (size_t)Lc * 3 * Dc * Dc;
    const size_t WPROJ = (size_t)Lc * Dc * Hc * HSc;
    const size_t WMLP  = (size_t)Lc * Dc * HIDc;
    unsigned short* wqkvT = (unsigned short*)alloc(WQKV * 2);
    unsigned short* woT = (unsigned short*)alloc(WPROJ * 2);
    unsigned short* wgT = (unsigned short*)alloc(WMLP * 2);
    unsigned short* w1T = (unsigned short*)alloc(WMLP * 2);
    unsigned short* w2T = (unsigned short*)alloc(WMLP * 2);
    float* ropeC = (float*)alloc((size_t)Tc * 32 * 4);
    float* ropeS = (float*)alloc((size_t)Tc * 32 * 4);
    unsigned short* xln  = (unsigned short*)alloc((size_t)Bc * Tc * Dc * 2);
    unsigned short* qbuf = (unsigned short*)alloc((size_t)Bc * Tc * Hc * HSc * 2);
    unsigned short* kbuf = (unsigned short*)alloc((size_t)Bc * Tc * Hc * HSc * 2);
    unsigned short* vbuf = (unsigned short*)alloc((size_t)Bc * Tc * Hc * HSc * 2);
    unsigned short* vtg  = (unsigned short*)alloc((size_t)Bc * Hc * HSc * Tc * 2);
    unsigned short* hbuf = (unsigned short*)alloc((size_t)Bc * Tc * HIDc * 2);
    float* psum = (float*)alloc((size_t)2 * Bc * Tc * Dc * 4);   // split-K partials (2 x 16MB)

    const dim3 b32(32, 8);
    const size_t qkvStride = (size_t)3 * Dc * Dc;
    transpose_cast_kernel<<<dim3(32, 32, 4), b32, 0, stream>>>(Wq, wqkvT, 1024, 1024, qkvStride, 0);
    transpose_cast_kernel<<<dim3(32, 32, 4), b32, 0, stream>>>(Wk, wqkvT, 1024, 1024, qkvStride, 1024);
    transpose_cast_kernel<<<dim3(32, 32, 4), b32, 0, stream>>>(Wv, wqkvT, 1024, 1024, qkvStride, 2048);
    transpose_cast_kernel<<<dim3(32, 32, 4), b32, 0, stream>>>(Wo, woT, 1024, 1024, (size_t)Dc * Dc, 0);
    transpose_cast_kernel<<<dim3(128, 32, 4), b32, 0, stream>>>(Wg, wgT, 1024, 4096, (size_t)Dc * HIDc, 0);
    transpose_cast_kernel<<<dim3(128, 32, 4), b32, 0, stream>>>(W1, w1T, 1024, 4096, (size_t)Dc * HIDc, 0);
    transpose_cast_kernel<<<dim3(32, 128, 4), b32, 0, stream>>>(W2, w2T, 4096, 1024, (size_t)Dc * HIDc, 0);
    rope_table_kernel<<<128, 256, 0, stream>>>(ropeC, ropeS);
    copy_f32_kernel<<<4096, 256, 0, stream>>>(x, xres, (Bc * Tc * Dc) / 4);

    const size_t zstr = (size_t)Bc * Tc * Dc;   // 4M elems per partial
    for (int l = 0; l < Lc; ++l) {
        const unsigned short* wqkv_l = wqkvT + (size_t)l * qkvStride;
        const unsigned short* wo_l = woT + (size_t)l * Dc * Dc;
        const unsigned short* wg_l = wgT + (size_t)l * Dc * HIDc;
        const unsigned short* w1_l = w1T + (size_t)l * Dc * HIDc;
        const unsigned short* w2_l = w2T + (size_t)l * Dc * HIDc;

        if (l == 0)
            rmsnorm_kernel<<<4096, 256, 0, stream>>>(xres, ln1 + l * Dc, xln);
        else  // fold previous layer's split-K down-proj partials into xres, then norm
            rmsnorm_add_kernel<<<4096, 256, 0, stream>>>(xres, psum, psum + zstr, ln1 + l * Dc, xln);
        // fused QKV: M=4096, N=3072, K=1024 -> 768 blocks (3/CU)
        gemm_bt_kernel<0><<<768, 256, 0, stream>>>(
            xln, wqkv_l, bq + l * 1024, bk + l * 1024, bv + l * 1024,
            qbuf, kbuf, vbuf, nullptr, nullptr, 3072, 1024, 1024, 0, 24);
        // merged q+k rope (blockIdx.y selects buffer)
        qk_rope_kernel<<<dim3(2048, 2), 256, 0, stream>>>(qbuf, kbuf, qsc + l * 64, ksc + l * 64,
                                                          ropeC, ropeS);
        vtrans_kernel<<<dim3(32, 2, 64), b32, 0, stream>>>(vbuf, vtg);
        attn_kernel<<<dim3(16, 16, 4), 256, 0, stream>>>(qbuf, kbuf, vtg, xln);
        // Wo: M=4096, N=1024, K=1024 full-K; residual += (with bias)
        gemm_bt_kernel<1><<<256, 256, 0, stream>>>(
            xln, wo_l, bo + l * 1024, nullptr, nullptr,
            nullptr, nullptr, nullptr, xres, xres, 1024, 1024, 1024, 0, 8);
        rmsnorm_kernel<<<4096, 256, 0, stream>>>(xres, ln2 + l * Dc, xln);
        // fused MLP gate+up (wave-specialized, 2 blocks/CU): 1024 blocks x 512 thr
        gemm_mlp_kernel<<<1024, 512, 0, stream>>>(xln, wg_l, w1_l, hbuf, 4096, 1024, 32);
        // down: M=4096, N=1024, K=4096 split-K x2 -> f32 partials (folded next layer)
        gemm_bt_kernel<4><<<dim3(256, 1, 2), 256, 0, stream>>>(
            hbuf, w2_l, nullptr, nullptr, nullptr,
            nullptr, nullptr, nullptr, nullptr, psum, 1024, 4096, 2048, zstr, 8);
    }
    // finalize last layer's residual
    reduce_res_kernel<<<4096, 256, 0, stream>>>(psum, psum + zstr, xres, (int)(zstr / 4));
}

// Round 13
// 1203.245 us; speedup vs baseline: 2.2530x; 1.0148x over previous
//
#include <hip/hip_runtime.h>

#define DI __device__ __forceinline__

typedef __attribute__((ext_vector_type(8))) __bf16 bf16x8;
typedef __attribute__((ext_vector_type(4))) float f32x4;
typedef __attribute__((ext_vector_type(4))) unsigned int u32x4;
typedef __attribute__((ext_vector_type(4))) unsigned short u16x4;

// Problem constants
static constexpr int Bc = 4, Tc = 1024, Dc = 1024, Hc = 16, HSc = 64, HIDc = 4096, Lc = 4;

DI unsigned short f2bf(float f) {
    union { float f; unsigned int u; } c; c.f = f;
    unsigned int u = c.u;
    u += 0x7fffu + ((u >> 16) & 1u);   // RNE
    return (unsigned short)(u >> 16);
}
DI float bf2f(unsigned short h) {
    union { unsigned int u; float f; } c; c.u = ((unsigned int)h) << 16;
    return c.f;
}

DI void gload_lds16(const void* g, void* l) {
    __builtin_amdgcn_global_load_lds((const __attribute__((address_space(1))) void*)g,
                                     (__attribute__((address_space(3))) void*)l, 16, 0, 0);
}

DI f32x4 mfma16x16x32(bf16x8 a, bf16x8 b, f32x4 c) {
    return __builtin_amdgcn_mfma_f32_16x16x32_bf16(a, b, c, 0, 0, 0);
}

// ---------------- weight transpose + f32->bf16 cast: W[l][K][N] -> Wt[l][rowOff+N][K] ----------------
__global__ __launch_bounds__(256) void transpose_cast_kernel(const float* __restrict__ W,
                                                             unsigned short* __restrict__ Wt,
                                                             int K, int N, size_t lstride, int rowOff) {
    __shared__ float tile[32][33];
    const int l = blockIdx.z;
    const float* Wl = W + (size_t)l * K * N;
    unsigned short* Wtl = Wt + (size_t)l * lstride;
    const int n0 = blockIdx.x * 32, k0 = blockIdx.y * 32;
    const int tx = threadIdx.x, ty = threadIdx.y;
#pragma unroll
    for (int i = 0; i < 32; i += 8) tile[ty + i][tx] = Wl[(size_t)(k0 + ty + i) * N + (n0 + tx)];
    __syncthreads();
#pragma unroll
    for (int i = 0; i < 32; i += 8)
        Wtl[(size_t)(rowOff + n0 + ty + i) * K + (k0 + tx)] = f2bf(tile[tx][ty + i]);
}

// ---------------- f32 copy (x -> residual in d_out) ----------------
__global__ __launch_bounds__(256) void copy_f32_kernel(const float* __restrict__ in,
                                                       float* __restrict__ out, int n4) {
    const int i = blockIdx.x * 256 + threadIdx.x;
    if (i < n4) ((f32x4*)out)[i] = ((const f32x4*)in)[i];
}

// ---------------- residual reduce: xres += p0 + p1 (split-K partials) ----------------
__global__ __launch_bounds__(256) void reduce_res_kernel(const float* __restrict__ p0,
                                                         const float* __restrict__ p1,
                                                         float* __restrict__ xres, int n4) {
    const int i = blockIdx.x * 256 + threadIdx.x;
    if (i < n4) {
        const f32x4 a = ((const f32x4*)p0)[i];
        const f32x4 b = ((const f32x4*)p1)[i];
        f32x4 r = ((f32x4*)xres)[i];
        r[0] += a[0] + b[0]; r[1] += a[1] + b[1]; r[2] += a[2] + b[2]; r[3] += a[3] + b[3];
        ((f32x4*)xres)[i] = r;
    }
}

// ---------------- RoPE sin/cos table [T][32] ----------------
__global__ __launch_bounds__(256) void rope_table_kernel(float* __restrict__ cosT,
                                                         float* __restrict__ sinT) {
    const int idx = blockIdx.x * 256 + threadIdx.x;  // T*32 = 32768
    const int t = idx >> 5, j = idx & 31;
    const float ts = powf(10000.f, (float)(2 * j) * (1.f / 64.f));
    const float ang = (float)t / ts;
    sinT[idx] = sinf(ang);
    cosT[idx] = cosf(ang);
}

// ---------------- RMSNorm over D=1024: f32 in -> bf16 out ----------------
__global__ __launch_bounds__(256) void rmsnorm_kernel(const float* __restrict__ x,
                                                      const float* __restrict__ scale,
                                                      unsigned short* __restrict__ out) {
    const int row = blockIdx.x;
    const int tid = threadIdx.x;
    const f32x4 v = ((const f32x4*)(x + (size_t)row * Dc))[tid];
    float ss = v[0] * v[0] + v[1] * v[1] + v[2] * v[2] + v[3] * v[3];
#pragma unroll
    for (int m = 32; m; m >>= 1) ss += __shfl_xor(ss, m);
    __shared__ float red[4];
    if ((tid & 63) == 0) red[tid >> 6] = ss;
    __syncthreads();
    const float tot = red[0] + red[1] + red[2] + red[3];
    const float r = rsqrtf(tot * (1.f / (float)Dc) + 1e-6f);
    const f32x4 sc = ((const f32x4*)scale)[tid];
    u16x4 o;
    o[0] = f2bf(v[0] * r * sc[0]);
    o[1] = f2bf(v[1] * r * sc[1]);
    o[2] = f2bf(v[2] * r * sc[2]);
    o[3] = f2bf(v[3] * r * sc[3]);
    *((u16x4*)(out + (size_t)row * Dc) + tid) = o;
}

// ---------------- RMSNorm + fold 2 split-K partials into xres, then norm ----------------
__global__ __launch_bounds__(256) void rmsnorm_add_kernel(float* __restrict__ xres,
                                                          const float* __restrict__ p0,
                                                          const float* __restrict__ p1,
                                                          const float* __restrict__ scale,
                                                          unsigned short* __restrict__ out) {
    const int row = blockIdx.x;
    const int tid = threadIdx.x;
    const size_t base = (size_t)row * Dc;
    f32x4 v = ((const f32x4*)(xres + base))[tid];
    const f32x4 a = ((const f32x4*)(p0 + base))[tid];
    const f32x4 b = ((const f32x4*)(p1 + base))[tid];
    v[0] += a[0] + b[0]; v[1] += a[1] + b[1]; v[2] += a[2] + b[2]; v[3] += a[3] + b[3];
    ((f32x4*)(xres + base))[tid] = v;
    float ss = v[0] * v[0] + v[1] * v[1] + v[2] * v[2] + v[3] * v[3];
#pragma unroll
    for (int m = 32; m; m >>= 1) ss += __shfl_xor(ss, m);
    __shared__ float red[4];
    if ((tid & 63) == 0) red[tid >> 6] = ss;
    __syncthreads();
    const float tot = red[0] + red[1] + red[2] + red[3];
    const float r = rsqrtf(tot * (1.f / (float)Dc) + 1e-6f);
    const f32x4 sc = ((const f32x4*)scale)[tid];
    u16x4 o;
    o[0] = f2bf(v[0] * r * sc[0]);
    o[1] = f2bf(v[1] * r * sc[1]);
    o[2] = f2bf(v[2] * r * sc[2]);
    o[3] = f2bf(v[3] * r * sc[3]);
    *((u16x4*)(out + (size_t)row * Dc) + tid) = o;
}

// ---------------- per-(b,t,h) RMSNorm over HS=64 + RoPE, in-place on bf16 (vectorized) ----------------
// blockIdx.y: 0 -> q, 1 -> k (merged dispatch)
__global__ __launch_bounds__(256) void qk_rope_kernel(unsigned short* __restrict__ q,
                                                      unsigned short* __restrict__ k,
                                                      const float* __restrict__ qscale,
                                                      const float* __restrict__ kscale,
                                                      const float* __restrict__ cosT,
                                                      const float* __restrict__ sinT) {
    unsigned short* buf = blockIdx.y ? k : q;
    const float* scl = blockIdx.y ? kscale : qscale;
    const int tid = threadIdx.x;
    const int sub = tid & 7;
    const size_t row = (size_t)blockIdx.x * 32 + (tid >> 3);   // index into [B*T*H]
    const int t = (int)((row >> 4) & (size_t)(Tc - 1));
    unsigned short* qr = buf + row * 64;
    const u32x4 pk = *(const u32x4*)(qr + sub * 8);
    float v[8];
#pragma unroll
    for (int i = 0; i < 4; ++i) {
        v[2 * i] = bf2f((unsigned short)(pk[i] & 0xffffu));
        v[2 * i + 1] = bf2f((unsigned short)(pk[i] >> 16));
    }
    float ss = 0.f;
#pragma unroll
    for (int i = 0; i < 8; ++i) ss += v[i] * v[i];
    ss += __shfl_xor(ss, 1, 8);
    ss += __shfl_xor(ss, 2, 8);
    ss += __shfl_xor(ss, 4, 8);
    const float rn = rsqrtf(ss * (1.f / 64.f) + 1e-6f);
    const f32x4 sc0 = ((const f32x4*)scl)[sub * 2];
    const f32x4 sc1 = ((const f32x4*)scl)[sub * 2 + 1];
    float xn[8];
#pragma unroll
    for (int i = 0; i < 8; ++i) xn[i] = v[i] * rn * (i < 4 ? sc0[i] : sc1[i - 4]);
    float other[8];
#pragma unroll
    for (int i = 0; i < 8; ++i) other[i] = __shfl_xor(xn[i], 4, 8);
    const int jb = (sub & 3) * 8;
    const f32x4 c0 = *(const f32x4*)(cosT + t * 32 + jb);
    const f32x4 c1 = *(const f32x4*)(cosT + t * 32 + jb + 4);
    const f32x4 s0 = *(const f32x4*)(sinT + t * 32 + jb);
    const f32x4 s1 = *(const f32x4*)(sinT + t * 32 + jb + 4);
    u32x4 o;
#pragma unroll
    for (int i = 0; i < 4; ++i) {
        const float ca = (2 * i < 4) ? c0[2 * i] : c1[2 * i - 4];
        const float cb = (2 * i + 1 < 4) ? c0[2 * i + 1] : c1[2 * i - 3];
        const float sa = (2 * i < 4) ? s0[2 * i] : s1[2 * i - 4];
        const float sb = (2 * i + 1 < 4) ? s0[2 * i + 1] : s1[2 * i - 3];
        float oa, ob;
        if (sub < 4) { oa = xn[2 * i] * ca - other[2 * i] * sa; ob = xn[2 * i + 1] * cb - other[2 * i + 1] * sb; }
        else         { oa = xn[2 * i] * ca + other[2 * i] * sa; ob = xn[2 * i + 1] * cb + other[2 * i + 1] * sb; }
        o[i] = (unsigned int)f2bf(oa) | ((unsigned int)f2bf(ob) << 16);
    }
    *(u32x4*)(qr + sub * 8) = o;
}

// ---------------- V transpose: [B,T,H,64] -> [B,H,64,T] (bf16) ----------------
__global__ __launch_bounds__(256) void vtrans_kernel(const unsigned short* __restrict__ v,
                                                     unsigned short* __restrict__ vt) {
    __shared__ unsigned short tile[32][33];
    const int bh = blockIdx.z, b = bh >> 4, h = bh & 15;
    const int t0 = blockIdx.x * 32, d0 = blockIdx.y * 32;
    const int tx = threadIdx.x, ty = threadIdx.y;
#pragma unroll
    for (int i = 0; i < 32; i += 8)
        tile[ty + i][tx] = v[(((size_t)b * Tc + (t0 + ty + i)) * Hc + h) * 64 + (d0 + tx)];
    __syncthreads();
#pragma unroll
    for (int i = 0; i < 32; i += 8)
        vt[(((size_t)b * Hc + h) * 64 + (d0 + ty + i)) * Tc + (t0 + tx)] = tile[tx][ty + i];
}

// ================= 128x128 m97-structure bf16 MFMA GEMM =================
// EPI 0: fused QKV (N=3072 -> 3x1024 outs), out = bf16(acc + bias)
// EPI 1: resout = resin + acc (+bias0 if non-null)   [f32, full-K only]
// EPI 4: resout[kz*zstride + idx] = acc               [f32 partial, split-K]
template <int EPI>
__global__ __launch_bounds__(256, 3) void gemm_bt_kernel(
    const unsigned short* __restrict__ A, const unsigned short* __restrict__ Bt,
    const float* __restrict__ bias0, const float* __restrict__ bias1, const float* __restrict__ bias2,
    unsigned short* __restrict__ out0, unsigned short* __restrict__ out1, unsigned short* __restrict__ out2,
    const float* __restrict__ resin, float* __restrict__ resout,
    int N, int K, int KZ, size_t zstride, int nbn) {
    __shared__ unsigned short As[128 * 64];
    __shared__ unsigned short Bs[128 * 64];
    const int tid = threadIdx.x, w = tid >> 6, l = tid & 63;
    const int wr = w >> 1, wc = w & 1;
    const int nwg = gridDim.x;
    const int t = (blockIdx.x & 7) * (nwg >> 3) + (blockIdx.x >> 3);
    const int st = t >> 6, r = t & 63;
    const int nsn = nbn >> 3;
    const int sm = st / nsn, sn = st - sm * nsn;
    const int bm = sm * 8 + (r >> 3), bn = sn * 8 + (r & 7);
    const int kz = blockIdx.z;

    const unsigned short* Ag = A + (size_t)bm * 128 * K + (size_t)kz * KZ;
    const unsigned short* Bg = Bt + (size_t)bn * 128 * K + (size_t)kz * KZ;
    const int nk = KZ >> 6;
    const int srow = (l >> 3);
    const int slc = (l & 7);

    f32x4 acc[4][4] = {};
    for (int kt = 0; kt < nk; ++kt) {
#pragma unroll
        for (int p = 0; p < 4; ++p) {
            const int row = w * 8 + p * 32 + srow;
            const int ce = slc ^ (row & 7);
            gload_lds16(Ag + (size_t)row * K + kt * 64 + ce * 8, &As[(w * 8 + p * 32) * 64]);
            gload_lds16(Bg + (size_t)row * K + kt * 64 + ce * 8, &Bs[(w * 8 + p * 32) * 64]);
        }
        __syncthreads();
        bf16x8 av[4][2], bv[4][2];
#pragma unroll
        for (int mf = 0; mf < 4; ++mf)
#pragma unroll
            for (int ks = 0; ks < 2; ++ks) {
                const int arow = wr * 64 + mf * 16 + (l & 15);
                av[mf][ks] = *(const bf16x8*)&As[arow * 64 + (((ks * 4 + (l >> 4)) ^ (arow & 7)) << 3)];
                const int brow = wc * 64 + mf * 16 + (l & 15);
                bv[mf][ks] = *(const bf16x8*)&Bs[brow * 64 + (((ks * 4 + (l >> 4)) ^ (brow & 7)) << 3)];
            }
#pragma unroll
        for (int mf = 0; mf < 4; ++mf)
#pragma unroll
            for (int nf = 0; nf < 4; ++nf)
#pragma unroll
                for (int ks = 0; ks < 2; ++ks)
                    acc[mf][nf] = mfma16x16x32(av[mf][ks], bv[nf][ks], acc[mf][nf]);
        __syncthreads();
    }

    // epilogue; C/D layout: col = lane&15, row = (lane>>4)*4 + reg
    const int r0 = bm * 128 + wr * 64 + ((l >> 4) << 2);
    if constexpr (EPI == 0) {
        const int sel = bn >> 3;
        const float* bias = sel == 0 ? bias0 : (sel == 1 ? bias1 : bias2);
        unsigned short* o = sel == 0 ? out0 : (sel == 1 ? out1 : out2);
        const int cb = (bn & 7) * 128 + wc * 64 + (l & 15);
#pragma unroll
        for (int nf = 0; nf < 4; ++nf) {
            const int col = cb + nf * 16;
            const float bvv = bias[col];
#pragma unroll
            for (int mf = 0; mf < 4; ++mf)
#pragma unroll
                for (int g = 0; g < 4; ++g)
                    o[(size_t)(r0 + mf * 16 + g) * 1024 + col] = f2bf(acc[mf][nf][g] + bvv);
        }
    } else {
        const int c0 = bn * 128 + wc * 64 + (l & 15);
        const size_t zoff = (size_t)kz * zstride;
#pragma unroll
        for (int nf = 0; nf < 4; ++nf) {
            const int col = c0 + nf * 16;
            float bvv = 0.f;
            if constexpr (EPI == 1) {
                if (bias0) bvv = bias0[col];
            }
#pragma unroll
            for (int mf = 0; mf < 4; ++mf)
#pragma unroll
                for (int g = 0; g < 4; ++g) {
                    const size_t idx = (size_t)(r0 + mf * 16 + g) * N + col;
                    const float val = acc[mf][nf][g];
                    if constexpr (EPI == 1) {
                        resout[idx] = resin[idx] + val + bvv;
                    } else {  // EPI == 4
                        resout[zoff + idx] = val;
                    }
                }
        }
    }
}

// ================= fused MLP gate+up, wave-specialized (proven best: (512,4), 2 blocks/CU) =================
// NOTE: (512,6) SPILLS — acc[4][4] = 64 AGPRs count against the unified VGPR/AGPR budget.
__global__ __launch_bounds__(512, 4) void gemm_mlp_kernel(
    const unsigned short* __restrict__ A, const unsigned short* __restrict__ Bg_,
    const unsigned short* __restrict__ Bu_, unsigned short* __restrict__ out,
    int N, int K, int nbn) {
    __shared__ unsigned short lds[3 * 128 * 64];   // As|Gs|Us; reused as P[128][132] in epilogue
    unsigned short* As = lds;
    unsigned short* Gs = lds + 128 * 64;
    unsigned short* Us = lds + 2 * 128 * 64;
    const int tid = threadIdx.x, w = tid >> 6, l = tid & 63;
    const int isUp = w >> 2;
    const int wq = w & 3;
    const int wr = wq >> 1, wc = wq & 1;
    const int nwg = gridDim.x;
    const int t = (blockIdx.x & 7) * (nwg >> 3) + (blockIdx.x >> 3);
    const int st = t >> 6, r = t & 63;
    const int nsn = nbn >> 3;
    const int sm = st / nsn, sn = st - sm * nsn;
    const int bm = sm * 8 + (r >> 3), bn = sn * 8 + (r & 7);

    const unsigned short* AgK = A + (size_t)bm * 128 * K;
    const unsigned short* GgK = Bg_ + (size_t)bn * 128 * K;
    const unsigned short* UgK = Bu_ + (size_t)bn * 128 * K;
    const unsigned short* Bs_my = isUp ? Us : Gs;
    const int nk = K >> 6;
    const int lr = l >> 3, slc = l & 7;

    f32x4 acc[4][4] = {};
    for (int kt = 0; kt < nk; ++kt) {
#pragma unroll
        for (int p = 0; p < 2; ++p) {
            const int rbase = p * 64 + w * 8;
            const int row = rbase + lr;
            const int ce = slc ^ (row & 7);
            gload_lds16(AgK + (size_t)row * K + kt * 64 + ce * 8, As + rbase * 64);
            gload_lds16(GgK + (size_t)row * K + kt * 64 + ce * 8, Gs + rbase * 64);
            gload_lds16(UgK + (size_t)row * K + kt * 64 + ce * 8, Us + rbase * 64);
        }
        __syncthreads();
#pragma unroll
        for (int ks = 0; ks < 2; ++ks) {
            bf16x8 av[4], bv[4];
#pragma unroll
            for (int mf = 0; mf < 4; ++mf) {
                const int arow = wr * 64 + mf * 16 + (l & 15);
                av[mf] = *(const bf16x8*)&As[arow * 64 + (((ks * 4 + (l >> 4)) ^ (arow & 7)) << 3)];
                const int brow = wc * 64 + mf * 16 + (l & 15);
                bv[mf] = *(const bf16x8*)&Bs_my[brow * 64 + (((ks * 4 + (l >> 4)) ^ (brow & 7)) << 3)];
            }
#pragma unroll
            for (int mf = 0; mf < 4; ++mf)
#pragma unroll
                for (int nf = 0; nf < 4; ++nf)
                    acc[mf][nf] = mfma16x16x32(av[mf], bv[nf], acc[mf][nf]);
        }
        __syncthreads();
    }

    // epilogue: gate waves write gelu(G) (bf16) to P; up waves multiply and store.
    unsigned short* P = lds;   // 128*132*2 = 33792 B, safe after last sync
    const int rl0 = wr * 64 + ((l >> 4) << 2);
    const int cl0 = wc * 64 + (l & 15);
    if (!isUp) {
#pragma unroll
        for (int nf = 0; nf < 4; ++nf)
#pragma unroll
            for (int mf = 0; mf < 4; ++mf)
#pragma unroll
                for (int g = 0; g < 4; ++g) {
                    const float gvl = acc[mf][nf][g];
                    const float z = 0.7978845608028654f * (gvl + 0.044715f * gvl * gvl * gvl);
                    P[(rl0 + mf * 16 + g) * 132 + cl0 + nf * 16] = f2bf(0.5f * gvl * (1.f + tanhf(z)));
                }
    }
    __syncthreads();
    if (isUp) {
        const int r0 = bm * 128 + rl0;
        const int c0 = bn * 128 + cl0;
#pragma unroll
        for (int nf = 0; nf < 4; ++nf)
#pragma unroll
            for (int mf = 0; mf < 4; ++mf)
#pragma unroll
                for (int g = 0; g < 4; ++g) {
                    const float p = bf2f(P[(rl0 + mf * 16 + g) * 132 + cl0 + nf * 16]);
                    out[(size_t)(r0 + mf * 16 + g) * N + (c0 + nf * 16)] = f2bf(p * acc[mf][nf][g]);
                }
    }
}

// ---------------- flash attention, QBLK=128 / 8 waves ----------------
// q,k [B,T,H,64]; vt [B,H,64,T]; out [B,T,H,64]. Each block: 128 q-rows, 16 K/V tiles of 64.
// K/V staged once per tile for 128 rows (half the stage traffic/row of QBLK=64).
// T14 reg-prefetch + T5 setprio around MFMA clusters.
__global__ __launch_bounds__(512, 4) void attn_kernel(const unsigned short* __restrict__ q,
                                                      const unsigned short* __restrict__ k,
                                                      const unsigned short* __restrict__ vt,
                                                      unsigned short* __restrict__ o) {
    constexpr int ST = 72;
    __shared__ unsigned short Qs[128 * ST], Ks[64 * ST], Vs[64 * ST], Ps[128 * ST];
    const int qb = blockIdx.x, h = blockIdx.y, b = blockIdx.z;
    const int tid = threadIdx.x, wid = tid >> 6, lane = tid & 63;
    const size_t qkbase = ((size_t)b << 20) + ((size_t)h << 6);
    const size_t vbase = ((size_t)(b * 16 + h)) << 16;
    // Q: 128 rows x 8 chunks = 1024 16B-loads / 512 thr = 2 each
#pragma unroll
    for (int p = 0; p < 2; ++p) {
        const int cid = tid + p * 512, r = cid >> 3, c = cid & 7;
        *(u32x4*)&Qs[r * ST + c * 8] =
            *(const u32x4*)&q[qkbase + (size_t)(qb * 128 + r) * 1024 + c * 8];
    }
    f32x4 oacc[4] = {};
    float mrun[4], lrun[4];
#pragma unroll
    for (int g = 0; g < 4; ++g) { mrun[g] = -1e30f; lrun[g] = 0.f; }
    const int fr = lane & 15, ko = (lane >> 4) * 8;
    // K/V tile: 64 rows x 8 chunks = 512 loads -> 1 per thread
    const int sr = tid >> 3, sc = tid & 7;
    u32x4 kr, vr;
    kr = *(const u32x4*)&k[qkbase + (size_t)sr * 1024 + sc * 8];
    vr = *(const u32x4*)&vt[vbase + (size_t)sr * 1024 + sc * 8];
    for (int j = 0; j < 16; ++j) {
        __syncthreads();  // prev PV done before overwriting Ks/Vs
        *(u32x4*)&Ks[sr * ST + sc * 8] = kr;
        *(u32x4*)&Vs[sr * ST + sc * 8] = vr;
        __syncthreads();
        if (j < 15) {   // prefetch next tile; HBM latency hides under compute below
            kr = *(const u32x4*)&k[qkbase + (size_t)((j + 1) * 64 + sr) * 1024 + sc * 8];
            vr = *(const u32x4*)&vt[vbase + (size_t)sr * 1024 + (j + 1) * 64 + sc * 8];
        }
        f32x4 sacc[4] = {};
        __builtin_amdgcn_s_setprio(1);
#pragma unroll
        for (int ks = 0; ks < 2; ++ks) {
            const bf16x8 a = *(const bf16x8*)&Qs[(wid * 16 + fr) * ST + ks * 32 + ko];
#pragma unroll
            for (int n = 0; n < 4; ++n) {
                const bf16x8 bb = *(const bf16x8*)&Ks[(n * 16 + fr) * ST + ks * 32 + ko];
                sacc[n] = mfma16x16x32(a, bb, sacc[n]);
            }
        }
        __builtin_amdgcn_s_setprio(0);
        float s[4][4];
#pragma unroll
        for (int n = 0; n < 4; ++n)
#pragma unroll
            for (int g = 0; g < 4; ++g) s[n][g] = sacc[n][g] * 0.125f;
        float rmax[4];
#pragma unroll
        for (int g = 0; g < 4; ++g)
            rmax[g] = fmaxf(fmaxf(s[0][g], s[1][g]), fmaxf(s[2][g], s[3][g]));
#pragma unroll
        for (int msk = 1; msk < 16; msk <<= 1)
#pragma unroll
            for (int g = 0; g < 4; ++g) rmax[g] = fmaxf(rmax[g], __shfl_xor(rmax[g], msk));
        float mn[4], alpha[4], rsum[4];
#pragma unroll
        for (int g = 0; g < 4; ++g) {
            mn[g] = fmaxf(mrun[g], rmax[g]);
            alpha[g] = __expf(mrun[g] - mn[g]);
            mrun[g] = mn[g];
            rsum[g] = 0.f;
        }
#pragma unroll
        for (int n = 0; n < 4; ++n)
#pragma unroll
            for (int g = 0; g < 4; ++g) {
                const float p = __expf(s[n][g] - mn[g]);
                rsum[g] += p;
                Ps[(wid * 16 + (lane >> 4) * 4 + g) * ST + n * 16 + (lane & 15)] = f2bf(p);
            }
#pragma unroll
        for (int msk = 1; msk < 16; msk <<= 1)
#pragma unroll
            for (int g = 0; g < 4; ++g) rsum[g] += __shfl_xor(rsum[g], msk);
#pragma unroll
        for (int g = 0; g < 4; ++g) lrun[g] = lrun[g] * alpha[g] + rsum[g];
#pragma unroll
        for (int nd = 0; nd < 4; ++nd)
#pragma unroll
            for (int g = 0; g < 4; ++g) oacc[nd][g] *= alpha[g];
        // PV: Ps rows are wave-local (same wave wrote them), Vs synced above
        __builtin_amdgcn_s_setprio(1);
#pragma unroll
        for (int ks = 0; ks < 2; ++ks) {
            const bf16x8 a = *(const bf16x8*)&Ps[(wid * 16 + fr) * ST + ks * 32 + ko];
#pragma unroll
            for (int nd = 0; nd < 4; ++nd) {
                const bf16x8 bb = *(const bf16x8*)&Vs[(nd * 16 + fr) * ST + ks * 32 + ko];
                oacc[nd] = mfma16x16x32(a, bb, oacc[nd]);
            }
        }
        __builtin_amdgcn_s_setprio(0);
    }
#pragma unroll
    for (int nd = 0; nd < 4; ++nd)
#pragma unroll
        for (int g = 0; g < 4; ++g) {
            const int r = qb * 128 + wid * 16 + (lane >> 4) * 4 + g;
            o[qkbase + (size_t)r * 1024 + nd * 16 + (lane & 15)] = f2bf(oacc[nd][g] / lrun[g]);
        }
}

extern "C" void kernel_launch(void* const* d_in, const int* in_sizes, int n_in,
                              void* d_out, int out_size, void* d_ws, size_t ws_size,
                              hipStream_t stream) {
    (void)in_sizes; (void)n_in; (void)out_size; (void)ws_size;
    const float* x   = (const float*)d_in[0];
    const float* Wq  = (const float*)d_in[2];
    const float* bq  = (const float*)d_in[3];
    const float* Wk  = (const float*)d_in[4];
    const float* bk  = (const float*)d_in[5];
    const float* Wv  = (const float*)d_in[6];
    const float* bv  = (const float*)d_in[7];
    const float* Wo  = (const float*)d_in[8];
    const float* bo  = (const float*)d_in[9];
    const float* qsc = (const float*)d_in[10];
    const float* ksc = (const float*)d_in[11];
    const float* ln1 = (const float*)d_in[12];
    const float* ln2 = (const float*)d_in[13];
    const float* Wg  = (const float*)d_in[14];
    const float* W1  = (const float*)d_in[15];
    const float* W2  = (const float*)d_in[16];
    float* xres = (float*)d_out;

    char* wsb = (char*)d_ws;
    size_t off = 0;
    auto alloc = [&](size_t bytes) -> char* {
        char* p = wsb + off;
        off += (bytes + 255) & ~(size_t)255;
        return p;
    };
    const size_t WQKV = (size_t)Lc * 3 * Dc * Dc;
    const size_t WPROJ = (size_t)Lc * Dc * Hc * HSc;
    const size_t WMLP  = (size_t)Lc * Dc * HIDc;
    unsigned short* wqkvT = (unsigned short*)alloc(WQKV * 2);
    unsigned short* woT = (unsigned short*)alloc(WPROJ * 2);
    unsigned short* wgT = (unsigned short*)alloc(WMLP * 2);
    unsigned short* w1T = (unsigned short*)alloc(WMLP * 2);
    unsigned short* w2T = (unsigned short*)alloc(WMLP * 2);
    float* ropeC = (float*)alloc((size_t)Tc * 32 * 4);
    float* ropeS = (float*)alloc((size_t)Tc * 32 * 4);
    unsigned short* xln  = (unsigned short*)alloc((size_t)Bc * Tc * Dc * 2);
    unsigned short* qbuf = (unsigned short*)alloc((size_t)Bc * Tc * Hc * HSc * 2);
    unsigned short* kbuf = (unsigned short*)alloc((size_t)Bc * Tc * Hc * HSc * 2);
    unsigned short* vbuf = (unsigned short*)alloc((size_t)Bc * Tc * Hc * HSc * 2);
    unsigned short* vtg  = (unsigned short*)alloc((size_t)Bc * Hc * HSc * Tc * 2);
    unsigned short* hbuf = (unsigned short*)alloc((size_t)Bc * Tc * HIDc * 2);
    float* psum = (float*)alloc((size_t)2 * Bc * Tc * Dc * 4);   // split-K partials (2 x 16MB)

    const dim3 b32(32, 8);
    const size_t qkvStride = (size_t)3 * Dc * Dc;
    transpose_cast_kernel<<<dim3(32, 32, 4), b32, 0, stream>>>(Wq, wqkvT, 1024, 1024, qkvStride, 0);
    transpose_cast_kernel<<<dim3(32, 32, 4), b32, 0, stream>>>(Wk, wqkvT, 1024, 1024, qkvStride, 1024);
    transpose_cast_kernel<<<dim3(32, 32, 4), b32, 0, stream>>>(Wv, wqkvT, 1024, 1024, qkvStride, 2048);
    transpose_cast_kernel<<<dim3(32, 32, 4), b32, 0, stream>>>(Wo, woT, 1024, 1024, (size_t)Dc * Dc, 0);
    transpose_cast_kernel<<<dim3(128, 32, 4), b32, 0, stream>>>(Wg, wgT, 1024, 4096, (size_t)Dc * HIDc, 0);
    transpose_cast_kernel<<<dim3(128, 32, 4), b32, 0, stream>>>(W1, w1T, 1024, 4096, (size_t)Dc * HIDc, 0);
    transpose_cast_kernel<<<dim3(32, 128, 4), b32, 0, stream>>>(W2, w2T, 4096, 1024, (size_t)Dc * HIDc, 0);
    rope_table_kernel<<<128, 256, 0, stream>>>(ropeC, ropeS);
    copy_f32_kernel<<<4096, 256, 0, stream>>>(x, xres, (Bc * Tc * Dc) / 4);

    const size_t zstr = (size_t)Bc * Tc * Dc;   // 4M elems per partial
    for (int l = 0; l < Lc; ++l) {
        const unsigned short* wqkv_l = wqkvT + (size_t)l * qkvStride;
        const unsigned short* wo_l = woT + (size_t)l * Dc * Dc;
        const unsigned short* wg_l = wgT + (size_t)l * Dc * HIDc;
        const unsigned short* w1_l = w1T + (size_t)l * Dc * HIDc;
        const unsigned short* w2_l = w2T + (size_t)l * Dc * HIDc;

        if (l == 0)
            rmsnorm_kernel<<<4096, 256, 0, stream>>>(xres, ln1 + l * Dc, xln);
        else  // fold previous layer's split-K down-proj partials into xres, then norm
            rmsnorm_add_kernel<<<4096, 256, 0, stream>>>(xres, psum, psum + zstr, ln1 + l * Dc, xln);
        // fused QKV: M=4096, N=3072, K=1024 -> 768 blocks (3/CU)
        gemm_bt_kernel<0><<<768, 256, 0, stream>>>(
            xln, wqkv_l, bq + l * 1024, bk + l * 1024, bv + l * 1024,
            qbuf, kbuf, vbuf, nullptr, nullptr, 3072, 1024, 1024, 0, 24);
        // merged q+k rope (blockIdx.y selects buffer)
        qk_rope_kernel<<<dim3(2048, 2), 256, 0, stream>>>(qbuf, kbuf, qsc + l * 64, ksc + l * 64,
                                                          ropeC, ropeS);
        vtrans_kernel<<<dim3(32, 2, 64), b32, 0, stream>>>(vbuf, vtg);
        // attention: QBLK=128 -> 8 q-blocks x 16 heads x 4 batch = 512 blocks x 512 thr
        attn_kernel<<<dim3(8, 16, 4), 512, 0, stream>>>(qbuf, kbuf, vtg, xln);
        // Wo: M=4096, N=1024, K=1024 full-K; residual += (with bias)
        gemm_bt_kernel<1><<<256, 256, 0, stream>>>(
            xln, wo_l, bo + l * 1024, nullptr, nullptr,
            nullptr, nullptr, nullptr, xres, xres, 1024, 1024, 1024, 0, 8);
        rmsnorm_kernel<<<4096, 256, 0, stream>>>(xres, ln2 + l * Dc, xln);
        // fused MLP gate+up (wave-specialized, 2 blocks/CU): 1024 blocks x 512 thr
        gemm_mlp_kernel<<<1024, 512, 0, stream>>>(xln, wg_l, w1_l, hbuf, 4096, 1024, 32);
        // down: M=4096, N=1024, K=4096 split-K x2 -> f32 partials (folded next layer)
        gemm_bt_kernel<4><<<dim3(256, 1, 2), 256, 0, stream>>>(
            hbuf, w2_l, nullptr, nullptr, nullptr,
            nullptr, nullptr, nullptr, nullptr, psum, 1024, 4096, 2048, zstr, 8);
    }
    // finalize last layer's residual
    reduce_res_kernel<<<4096, 256, 0, stream>>>(psum, psum + zstr, xres, (int)(zstr / 4));
}

// Round 14
// 1184.551 us; speedup vs baseline: 2.2885x; 1.0158x over previous
//
#include <hip/hip_runtime.h>

#define DI __device__ __forceinline__

typedef __attribute__((ext_vector_type(8))) __bf16 bf16x8;
typedef __attribute__((ext_vector_type(4))) float f32x4;
typedef __attribute__((ext_vector_type(4))) unsigned int u32x4;
typedef __attribute__((ext_vector_type(4))) unsigned short u16x4;

// Problem constants
static constexpr int Bc = 4, Tc = 1024, Dc = 1024, Hc = 16, HSc = 64, HIDc = 4096, Lc = 4;

DI unsigned short f2bf(float f) {
    union { float f; unsigned int u; } c; c.f = f;
    unsigned int u = c.u;
    u += 0x7fffu + ((u >> 16) & 1u);   // RNE
    return (unsigned short)(u >> 16);
}
DI float bf2f(unsigned short h) {
    union { unsigned int u; float f; } c; c.u = ((unsigned int)h) << 16;
    return c.f;
}

DI void gload_lds16(const void* g, void* l) {
    __builtin_amdgcn_global_load_lds((const __attribute__((address_space(1))) void*)g,
                                     (__attribute__((address_space(3))) void*)l, 16, 0, 0);
}

DI f32x4 mfma16x16x32(bf16x8 a, bf16x8 b, f32x4 c) {
    return __builtin_amdgcn_mfma_f32_16x16x32_bf16(a, b, c, 0, 0, 0);
}

// ---------------- weight transpose + f32->bf16 cast: W[l][K][N] -> Wt[l][rowOff+N][K] ----------------
__global__ __launch_bounds__(256) void transpose_cast_kernel(const float* __restrict__ W,
                                                             unsigned short* __restrict__ Wt,
                                                             int K, int N, size_t lstride, int rowOff) {
    __shared__ float tile[32][33];
    const int l = blockIdx.z;
    const float* Wl = W + (size_t)l * K * N;
    unsigned short* Wtl = Wt + (size_t)l * lstride;
    const int n0 = blockIdx.x * 32, k0 = blockIdx.y * 32;
    const int tx = threadIdx.x, ty = threadIdx.y;
#pragma unroll
    for (int i = 0; i < 32; i += 8) tile[ty + i][tx] = Wl[(size_t)(k0 + ty + i) * N + (n0 + tx)];
    __syncthreads();
#pragma unroll
    for (int i = 0; i < 32; i += 8)
        Wtl[(size_t)(rowOff + n0 + ty + i) * K + (k0 + tx)] = f2bf(tile[tx][ty + i]);
}

// ---------------- residual reduce: xres += p0 + p1 (split-K partials) ----------------
__global__ __launch_bounds__(256) void reduce_res_kernel(const float* __restrict__ p0,
                                                         const float* __restrict__ p1,
                                                         float* __restrict__ xres, int n4) {
    const int i = blockIdx.x * 256 + threadIdx.x;
    if (i < n4) {
        const f32x4 a = ((const f32x4*)p0)[i];
        const f32x4 b = ((const f32x4*)p1)[i];
        f32x4 r = ((f32x4*)xres)[i];
        r[0] += a[0] + b[0]; r[1] += a[1] + b[1]; r[2] += a[2] + b[2]; r[3] += a[3] + b[3];
        ((f32x4*)xres)[i] = r;
    }
}

// ---------------- RoPE sin/cos table [T][32] ----------------
__global__ __launch_bounds__(256) void rope_table_kernel(float* __restrict__ cosT,
                                                         float* __restrict__ sinT) {
    const int idx = blockIdx.x * 256 + threadIdx.x;  // T*32 = 32768
    const int t = idx >> 5, j = idx & 31;
    const float ts = powf(10000.f, (float)(2 * j) * (1.f / 64.f));
    const float ang = (float)t / ts;
    sinT[idx] = sinf(ang);
    cosT[idx] = cosf(ang);
}

// ---------------- RMSNorm over D=1024 + copy x->xres (layer 0): f32 in -> bf16 out ----------------
__global__ __launch_bounds__(256) void rmsnorm_copy_kernel(const float* __restrict__ x,
                                                           float* __restrict__ xres,
                                                           const float* __restrict__ scale,
                                                           unsigned short* __restrict__ out) {
    const int row = blockIdx.x;
    const int tid = threadIdx.x;
    const f32x4 v = ((const f32x4*)(x + (size_t)row * Dc))[tid];
    ((f32x4*)(xres + (size_t)row * Dc))[tid] = v;
    float ss = v[0] * v[0] + v[1] * v[1] + v[2] * v[2] + v[3] * v[3];
#pragma unroll
    for (int m = 32; m; m >>= 1) ss += __shfl_xor(ss, m);
    __shared__ float red[4];
    if ((tid & 63) == 0) red[tid >> 6] = ss;
    __syncthreads();
    const float tot = red[0] + red[1] + red[2] + red[3];
    const float r = rsqrtf(tot * (1.f / (float)Dc) + 1e-6f);
    const f32x4 sc = ((const f32x4*)scale)[tid];
    u16x4 o;
    o[0] = f2bf(v[0] * r * sc[0]);
    o[1] = f2bf(v[1] * r * sc[1]);
    o[2] = f2bf(v[2] * r * sc[2]);
    o[3] = f2bf(v[3] * r * sc[3]);
    *((u16x4*)(out + (size_t)row * Dc) + tid) = o;
}

// ---------------- RMSNorm over D=1024: f32 in -> bf16 out ----------------
__global__ __launch_bounds__(256) void rmsnorm_kernel(const float* __restrict__ x,
                                                      const float* __restrict__ scale,
                                                      unsigned short* __restrict__ out) {
    const int row = blockIdx.x;
    const int tid = threadIdx.x;
    const f32x4 v = ((const f32x4*)(x + (size_t)row * Dc))[tid];
    float ss = v[0] * v[0] + v[1] * v[1] + v[2] * v[2] + v[3] * v[3];
#pragma unroll
    for (int m = 32; m; m >>= 1) ss += __shfl_xor(ss, m);
    __shared__ float red[4];
    if ((tid & 63) == 0) red[tid >> 6] = ss;
    __syncthreads();
    const float tot = red[0] + red[1] + red[2] + red[3];
    const float r = rsqrtf(tot * (1.f / (float)Dc) + 1e-6f);
    const f32x4 sc = ((const f32x4*)scale)[tid];
    u16x4 o;
    o[0] = f2bf(v[0] * r * sc[0]);
    o[1] = f2bf(v[1] * r * sc[1]);
    o[2] = f2bf(v[2] * r * sc[2]);
    o[3] = f2bf(v[3] * r * sc[3]);
    *((u16x4*)(out + (size_t)row * Dc) + tid) = o;
}

// ---------------- RMSNorm + fold 2 split-K partials into xres, then norm ----------------
__global__ __launch_bounds__(256) void rmsnorm_add_kernel(float* __restrict__ xres,
                                                          const float* __restrict__ p0,
                                                          const float* __restrict__ p1,
                                                          const float* __restrict__ scale,
                                                          unsigned short* __restrict__ out) {
    const int row = blockIdx.x;
    const int tid = threadIdx.x;
    const size_t base = (size_t)row * Dc;
    f32x4 v = ((const f32x4*)(xres + base))[tid];
    const f32x4 a = ((const f32x4*)(p0 + base))[tid];
    const f32x4 b = ((const f32x4*)(p1 + base))[tid];
    v[0] += a[0] + b[0]; v[1] += a[1] + b[1]; v[2] += a[2] + b[2]; v[3] += a[3] + b[3];
    ((f32x4*)(xres + base))[tid] = v;
    float ss = v[0] * v[0] + v[1] * v[1] + v[2] * v[2] + v[3] * v[3];
#pragma unroll
    for (int m = 32; m; m >>= 1) ss += __shfl_xor(ss, m);
    __shared__ float red[4];
    if ((tid & 63) == 0) red[tid >> 6] = ss;
    __syncthreads();
    const float tot = red[0] + red[1] + red[2] + red[3];
    const float r = rsqrtf(tot * (1.f / (float)Dc) + 1e-6f);
    const f32x4 sc = ((const f32x4*)scale)[tid];
    u16x4 o;
    o[0] = f2bf(v[0] * r * sc[0]);
    o[1] = f2bf(v[1] * r * sc[1]);
    o[2] = f2bf(v[2] * r * sc[2]);
    o[3] = f2bf(v[3] * r * sc[3]);
    *((u16x4*)(out + (size_t)row * Dc) + tid) = o;
}

// ---------------- per-(b,t,h) RMSNorm over HS=64 + RoPE, in-place on bf16 (vectorized) ----------------
// blockIdx.y: 0 -> q, 1 -> k (merged dispatch)
__global__ __launch_bounds__(256) void qk_rope_kernel(unsigned short* __restrict__ q,
                                                      unsigned short* __restrict__ k,
                                                      const float* __restrict__ qscale,
                                                      const float* __restrict__ kscale,
                                                      const float* __restrict__ cosT,
                                                      const float* __restrict__ sinT) {
    unsigned short* buf = blockIdx.y ? k : q;
    const float* scl = blockIdx.y ? kscale : qscale;
    const int tid = threadIdx.x;
    const int sub = tid & 7;
    const size_t row = (size_t)blockIdx.x * 32 + (tid >> 3);   // index into [B*T*H]
    const int t = (int)((row >> 4) & (size_t)(Tc - 1));
    unsigned short* qr = buf + row * 64;
    const u32x4 pk = *(const u32x4*)(qr + sub * 8);
    float v[8];
#pragma unroll
    for (int i = 0; i < 4; ++i) {
        v[2 * i] = bf2f((unsigned short)(pk[i] & 0xffffu));
        v[2 * i + 1] = bf2f((unsigned short)(pk[i] >> 16));
    }
    float ss = 0.f;
#pragma unroll
    for (int i = 0; i < 8; ++i) ss += v[i] * v[i];
    ss += __shfl_xor(ss, 1, 8);
    ss += __shfl_xor(ss, 2, 8);
    ss += __shfl_xor(ss, 4, 8);
    const float rn = rsqrtf(ss * (1.f / 64.f) + 1e-6f);
    const f32x4 sc0 = ((const f32x4*)scl)[sub * 2];
    const f32x4 sc1 = ((const f32x4*)scl)[sub * 2 + 1];
    float xn[8];
#pragma unroll
    for (int i = 0; i < 8; ++i) xn[i] = v[i] * rn * (i < 4 ? sc0[i] : sc1[i - 4]);
    float other[8];
#pragma unroll
    for (int i = 0; i < 8; ++i) other[i] = __shfl_xor(xn[i], 4, 8);
    const int jb = (sub & 3) * 8;
    const f32x4 c0 = *(const f32x4*)(cosT + t * 32 + jb);
    const f32x4 c1 = *(const f32x4*)(cosT + t * 32 + jb + 4);
    const f32x4 s0 = *(const f32x4*)(sinT + t * 32 + jb);
    const f32x4 s1 = *(const f32x4*)(sinT + t * 32 + jb + 4);
    u32x4 o;
#pragma unroll
    for (int i = 0; i < 4; ++i) {
        const float ca = (2 * i < 4) ? c0[2 * i] : c1[2 * i - 4];
        const float cb = (2 * i + 1 < 4) ? c0[2 * i + 1] : c1[2 * i - 3];
        const float sa = (2 * i < 4) ? s0[2 * i] : s1[2 * i - 4];
        const float sb = (2 * i + 1 < 4) ? s0[2 * i + 1] : s1[2 * i - 3];
        float oa, ob;
        if (sub < 4) { oa = xn[2 * i] * ca - other[2 * i] * sa; ob = xn[2 * i + 1] * cb - other[2 * i + 1] * sb; }
        else         { oa = xn[2 * i] * ca + other[2 * i] * sa; ob = xn[2 * i + 1] * cb + other[2 * i + 1] * sb; }
        o[i] = (unsigned int)f2bf(oa) | ((unsigned int)f2bf(ob) << 16);
    }
    *(u32x4*)(qr + sub * 8) = o;
}

// ================= 128x128 m97-structure bf16 MFMA GEMM =================
// EPI 0: fused QKV (N=3072): q,k -> bf16 [B,T,H,64]+bias; V -> TRANSPOSED vtg [B,H,64,T]+bias
// EPI 1: resout = resin + acc (+bias0 if non-null)   [f32, full-K only]
// EPI 4: resout[kz*zstride + idx] = acc               [f32 partial, split-K]
template <int EPI>
__global__ __launch_bounds__(256, 3) void gemm_bt_kernel(
    const unsigned short* __restrict__ A, const unsigned short* __restrict__ Bt,
    const float* __restrict__ bias0, const float* __restrict__ bias1, const float* __restrict__ bias2,
    unsigned short* __restrict__ out0, unsigned short* __restrict__ out1, unsigned short* __restrict__ out2,
    const float* __restrict__ resin, float* __restrict__ resout,
    int N, int K, int KZ, size_t zstride, int nbn) {
    __shared__ unsigned short As[128 * 64];
    __shared__ unsigned short Bs[128 * 64];
    const int tid = threadIdx.x, w = tid >> 6, l = tid & 63;
    const int wr = w >> 1, wc = w & 1;
    const int nwg = gridDim.x;
    const int t = (blockIdx.x & 7) * (nwg >> 3) + (blockIdx.x >> 3);
    const int st = t >> 6, r = t & 63;
    const int nsn = nbn >> 3;
    const int sm = st / nsn, sn = st - sm * nsn;
    const int bm = sm * 8 + (r >> 3), bn = sn * 8 + (r & 7);
    const int kz = blockIdx.z;

    const unsigned short* Ag = A + (size_t)bm * 128 * K + (size_t)kz * KZ;
    const unsigned short* Bg = Bt + (size_t)bn * 128 * K + (size_t)kz * KZ;
    const int nk = KZ >> 6;
    const int srow = (l >> 3);
    const int slc = (l & 7);

    f32x4 acc[4][4] = {};
    for (int kt = 0; kt < nk; ++kt) {
#pragma unroll
        for (int p = 0; p < 4; ++p) {
            const int row = w * 8 + p * 32 + srow;
            const int ce = slc ^ (row & 7);
            gload_lds16(Ag + (size_t)row * K + kt * 64 + ce * 8, &As[(w * 8 + p * 32) * 64]);
            gload_lds16(Bg + (size_t)row * K + kt * 64 + ce * 8, &Bs[(w * 8 + p * 32) * 64]);
        }
        __syncthreads();
        bf16x8 av[4][2], bv[4][2];
#pragma unroll
        for (int mf = 0; mf < 4; ++mf)
#pragma unroll
            for (int ks = 0; ks < 2; ++ks) {
                const int arow = wr * 64 + mf * 16 + (l & 15);
                av[mf][ks] = *(const bf16x8*)&As[arow * 64 + (((ks * 4 + (l >> 4)) ^ (arow & 7)) << 3)];
                const int brow = wc * 64 + mf * 16 + (l & 15);
                bv[mf][ks] = *(const bf16x8*)&Bs[brow * 64 + (((ks * 4 + (l >> 4)) ^ (brow & 7)) << 3)];
            }
#pragma unroll
        for (int mf = 0; mf < 4; ++mf)
#pragma unroll
            for (int nf = 0; nf < 4; ++nf)
#pragma unroll
                for (int ks = 0; ks < 2; ++ks)
                    acc[mf][nf] = mfma16x16x32(av[mf][ks], bv[nf][ks], acc[mf][nf]);
        __syncthreads();
    }

    // epilogue; C/D layout: col = lane&15, row = (lane>>4)*4 + reg
    const int r0 = bm * 128 + wr * 64 + ((l >> 4) << 2);
    if constexpr (EPI == 0) {
        const int sel = bn >> 3;
        const float* bias = sel == 0 ? bias0 : (sel == 1 ? bias1 : bias2);
        const int cb = (bn & 7) * 128 + wc * 64 + (l & 15);
        if (sel < 2) {
            unsigned short* o = sel == 0 ? out0 : out1;
#pragma unroll
            for (int nf = 0; nf < 4; ++nf) {
                const int col = cb + nf * 16;
                const float bvv = bias[col];
#pragma unroll
                for (int mf = 0; mf < 4; ++mf)
#pragma unroll
                    for (int g = 0; g < 4; ++g)
                        o[(size_t)(r0 + mf * 16 + g) * 1024 + col] = f2bf(acc[mf][nf][g] + bvv);
            }
        } else {
            // V: write transposed into vtg [B,H,64,T]; row r_g=(b,t), col=(h,d)
            // consecutive g = consecutive tokens = contiguous in vtg
#pragma unroll
            for (int nf = 0; nf < 4; ++nf) {
                const int col = cb + nf * 16;
                const float bvv = bias[col];
                const size_t vrow = ((size_t)col) << 10;   // ((b?*16+h)*64+d) base via col, b folded below
#pragma unroll
                for (int mf = 0; mf < 4; ++mf) {
                    const int rg = r0 + mf * 16;           // rg..rg+3 tokens (same b: 128-tile within batch)
                    const int b = rg >> 10, tt = rg & 1023;
                    unsigned short* dst = out2 + (((size_t)b << 20) + vrow) + tt;
#pragma unroll
                    for (int g = 0; g < 4; ++g)
                        dst[g] = f2bf(acc[mf][nf][g] + bvv);
                }
            }
        }
    } else {
        const int c0 = bn * 128 + wc * 64 + (l & 15);
        const size_t zoff = (size_t)kz * zstride;
#pragma unroll
        for (int nf = 0; nf < 4; ++nf) {
            const int col = c0 + nf * 16;
            float bvv = 0.f;
            if constexpr (EPI == 1) {
                if (bias0) bvv = bias0[col];
            }
#pragma unroll
            for (int mf = 0; mf < 4; ++mf)
#pragma unroll
                for (int g = 0; g < 4; ++g) {
                    const size_t idx = (size_t)(r0 + mf * 16 + g) * N + col;
                    const float val = acc[mf][nf][g];
                    if constexpr (EPI == 1) {
                        resout[idx] = resin[idx] + val + bvv;
                    } else {  // EPI == 4
                        resout[zoff + idx] = val;
                    }
                }
        }
    }
}

// ================= fused MLP gate+up, wave-specialized (proven best: (512,4), 2 blocks/CU) =================
// NOTE: (512,6) SPILLS — acc[4][4] = 64 AGPRs count against the unified VGPR/AGPR budget.
__global__ __launch_bounds__(512, 4) void gemm_mlp_kernel(
    const unsigned short* __restrict__ A, const unsigned short* __restrict__ Bg_,
    const unsigned short* __restrict__ Bu_, unsigned short* __restrict__ out,
    int N, int K, int nbn) {
    __shared__ unsigned short lds[3 * 128 * 64];   // As|Gs|Us; reused as P[128][132] in epilogue
    unsigned short* As = lds;
    unsigned short* Gs = lds + 128 * 64;
    unsigned short* Us = lds + 2 * 128 * 64;
    const int tid = threadIdx.x, w = tid >> 6, l = tid & 63;
    const int isUp = w >> 2;
    const int wq = w & 3;
    const int wr = wq >> 1, wc = wq & 1;
    const int nwg = gridDim.x;
    const int t = (blockIdx.x & 7) * (nwg >> 3) + (blockIdx.x >> 3);
    const int st = t >> 6, r = t & 63;
    const int nsn = nbn >> 3;
    const int sm = st / nsn, sn = st - sm * nsn;
    const int bm = sm * 8 + (r >> 3), bn = sn * 8 + (r & 7);

    const unsigned short* AgK = A + (size_t)bm * 128 * K;
    const unsigned short* GgK = Bg_ + (size_t)bn * 128 * K;
    const unsigned short* UgK = Bu_ + (size_t)bn * 128 * K;
    const unsigned short* Bs_my = isUp ? Us : Gs;
    const int nk = K >> 6;
    const int lr = l >> 3, slc = l & 7;

    f32x4 acc[4][4] = {};
    for (int kt = 0; kt < nk; ++kt) {
#pragma unroll
        for (int p = 0; p < 2; ++p) {
            const int rbase = p * 64 + w * 8;
            const int row = rbase + lr;
            const int ce = slc ^ (row & 7);
            gload_lds16(AgK + (size_t)row * K + kt * 64 + ce * 8, As + rbase * 64);
            gload_lds16(GgK + (size_t)row * K + kt * 64 + ce * 8, Gs + rbase * 64);
            gload_lds16(UgK + (size_t)row * K + kt * 64 + ce * 8, Us + rbase * 64);
        }
        __syncthreads();
#pragma unroll
        for (int ks = 0; ks < 2; ++ks) {
            bf16x8 av[4], bv[4];
#pragma unroll
            for (int mf = 0; mf < 4; ++mf) {
                const int arow = wr * 64 + mf * 16 + (l & 15);
                av[mf] = *(const bf16x8*)&As[arow * 64 + (((ks * 4 + (l >> 4)) ^ (arow & 7)) << 3)];
                const int brow = wc * 64 + mf * 16 + (l & 15);
                bv[mf] = *(const bf16x8*)&Bs_my[brow * 64 + (((ks * 4 + (l >> 4)) ^ (brow & 7)) << 3)];
            }
#pragma unroll
            for (int mf = 0; mf < 4; ++mf)
#pragma unroll
                for (int nf = 0; nf < 4; ++nf)
                    acc[mf][nf] = mfma16x16x32(av[mf], bv[nf], acc[mf][nf]);
        }
        __syncthreads();
    }

    // epilogue: gate waves write gelu(G) (bf16) to P; up waves multiply and store.
    unsigned short* P = lds;   // 128*132*2 = 33792 B, safe after last sync
    const int rl0 = wr * 64 + ((l >> 4) << 2);
    const int cl0 = wc * 64 + (l & 15);
    if (!isUp) {
#pragma unroll
        for (int nf = 0; nf < 4; ++nf)
#pragma unroll
            for (int mf = 0; mf < 4; ++mf)
#pragma unroll
                for (int g = 0; g < 4; ++g) {
                    const float gvl = acc[mf][nf][g];
                    const float z = 0.7978845608028654f * (gvl + 0.044715f * gvl * gvl * gvl);
                    P[(rl0 + mf * 16 + g) * 132 + cl0 + nf * 16] = f2bf(0.5f * gvl * (1.f + tanhf(z)));
                }
    }
    __syncthreads();
    if (isUp) {
        const int r0 = bm * 128 + rl0;
        const int c0 = bn * 128 + cl0;
#pragma unroll
        for (int nf = 0; nf < 4; ++nf)
#pragma unroll
            for (int mf = 0; mf < 4; ++mf)
#pragma unroll
                for (int g = 0; g < 4; ++g) {
                    const float p = bf2f(P[(rl0 + mf * 16 + g) * 132 + cl0 + nf * 16]);
                    out[(size_t)(r0 + mf * 16 + g) * N + (c0 + nf * 16)] = f2bf(p * acc[mf][nf][g]);
                }
    }
}

// ---------------- flash attention, QBLK=128 / 8 waves ----------------
// q,k [B,T,H,64]; vt [B,H,64,T]; out [B,T,H,64]. T14 reg-prefetch + T5 setprio.
__global__ __launch_bounds__(512, 4) void attn_kernel(const unsigned short* __restrict__ q,
                                                      const unsigned short* __restrict__ k,
                                                      const unsigned short* __restrict__ vt,
                                                      unsigned short* __restrict__ o) {
    constexpr int ST = 72;
    __shared__ unsigned short Qs[128 * ST], Ks[64 * ST], Vs[64 * ST], Ps[128 * ST];
    const int qb = blockIdx.x, h = blockIdx.y, b = blockIdx.z;
    const int tid = threadIdx.x, wid = tid >> 6, lane = tid & 63;
    const size_t qkbase = ((size_t)b << 20) + ((size_t)h << 6);
    const size_t vbase = ((size_t)(b * 16 + h)) << 16;
#pragma unroll
    for (int p = 0; p < 2; ++p) {
        const int cid = tid + p * 512, r = cid >> 3, c = cid & 7;
        *(u32x4*)&Qs[r * ST + c * 8] =
            *(const u32x4*)&q[qkbase + (size_t)(qb * 128 + r) * 1024 + c * 8];
    }
    f32x4 oacc[4] = {};
    float mrun[4], lrun[4];
#pragma unroll
    for (int g = 0; g < 4; ++g) { mrun[g] = -1e30f; lrun[g] = 0.f; }
    const int fr = lane & 15, ko = (lane >> 4) * 8;
    const int sr = tid >> 3, sc = tid & 7;
    u32x4 kr, vr;
    kr = *(const u32x4*)&k[qkbase + (size_t)sr * 1024 + sc * 8];
    vr = *(const u32x4*)&vt[vbase + (size_t)sr * 1024 + sc * 8];
    for (int j = 0; j < 16; ++j) {
        __syncthreads();
        *(u32x4*)&Ks[sr * ST + sc * 8] = kr;
        *(u32x4*)&Vs[sr * ST + sc * 8] = vr;
        __syncthreads();
        if (j < 15) {
            kr = *(const u32x4*)&k[qkbase + (size_t)((j + 1) * 64 + sr) * 1024 + sc * 8];
            vr = *(const u32x4*)&vt[vbase + (size_t)sr * 1024 + (j + 1) * 64 + sc * 8];
        }
        f32x4 sacc[4] = {};
        __builtin_amdgcn_s_setprio(1);
#pragma unroll
        for (int ks = 0; ks < 2; ++ks) {
            const bf16x8 a = *(const bf16x8*)&Qs[(wid * 16 + fr) * ST + ks * 32 + ko];
#pragma unroll
            for (int n = 0; n < 4; ++n) {
                const bf16x8 bb = *(const bf16x8*)&Ks[(n * 16 + fr) * ST + ks * 32 + ko];
                sacc[n] = mfma16x16x32(a, bb, sacc[n]);
            }
        }
        __builtin_amdgcn_s_setprio(0);
        float s[4][4];
#pragma unroll
        for (int n = 0; n < 4; ++n)
#pragma unroll
            for (int g = 0; g < 4; ++g) s[n][g] = sacc[n][g] * 0.125f;
        float rmax[4];
#pragma unroll
        for (int g = 0; g < 4; ++g)
            rmax[g] = fmaxf(fmaxf(s[0][g], s[1][g]), fmaxf(s[2][g], s[3][g]));
#pragma unroll
        for (int msk = 1; msk < 16; msk <<= 1)
#pragma unroll
            for (int g = 0; g < 4; ++g) rmax[g] = fmaxf(rmax[g], __shfl_xor(rmax[g], msk));
        float mn[4], alpha[4], rsum[4];
#pragma unroll
        for (int g = 0; g < 4; ++g) {
            mn[g] = fmaxf(mrun[g], rmax[g]);
            alpha[g] = __expf(mrun[g] - mn[g]);
            mrun[g] = mn[g];
            rsum[g] = 0.f;
        }
#pragma unroll
        for (int n = 0; n < 4; ++n)
#pragma unroll
            for (int g = 0; g < 4; ++g) {
                const float p = __expf(s[n][g] - mn[g]);
                rsum[g] += p;
                Ps[(wid * 16 + (lane >> 4) * 4 + g) * ST + n * 16 + (lane & 15)] = f2bf(p);
            }
#pragma unroll
        for (int msk = 1; msk < 16; msk <<= 1)
#pragma unroll
            for (int g = 0; g < 4; ++g) rsum[g] += __shfl_xor(rsum[g], msk);
#pragma unroll
        for (int g = 0; g < 4; ++g) lrun[g] = lrun[g] * alpha[g] + rsum[g];
#pragma unroll
        for (int nd = 0; nd < 4; ++nd)
#pragma unroll
            for (int g = 0; g < 4; ++g) oacc[nd][g] *= alpha[g];
        __builtin_amdgcn_s_setprio(1);
#pragma unroll
        for (int ks = 0; ks < 2; ++ks) {
            const bf16x8 a = *(const bf16x8*)&Ps[(wid * 16 + fr) * ST + ks * 32 + ko];
#pragma unroll
            for (int nd = 0; nd < 4; ++nd) {
                const bf16x8 bb = *(const bf16x8*)&Vs[(nd * 16 + fr) * ST + ks * 32 + ko];
                oacc[nd] = mfma16x16x32(a, bb, oacc[nd]);
            }
        }
        __builtin_amdgcn_s_setprio(0);
    }
#pragma unroll
    for (int nd = 0; nd < 4; ++nd)
#pragma unroll
        for (int g = 0; g < 4; ++g) {
            const int r = qb * 128 + wid * 16 + (lane >> 4) * 4 + g;
            o[qkbase + (size_t)r * 1024 + nd * 16 + (lane & 15)] = f2bf(oacc[nd][g] / lrun[g]);
        }
}

extern "C" void kernel_launch(void* const* d_in, const int* in_sizes, int n_in,
                              void* d_out, int out_size, void* d_ws, size_t ws_size,
                              hipStream_t stream) {
    (void)in_sizes; (void)n_in; (void)out_size; (void)ws_size;
    const float* x   = (const float*)d_in[0];
    const float* Wq  = (const float*)d_in[2];
    const float* bq  = (const float*)d_in[3];
    const float* Wk  = (const float*)d_in[4];
    const float* bk  = (const float*)d_in[5];
    const float* Wv  = (const float*)d_in[6];
    const float* bv  = (const float*)d_in[7];
    const float* Wo  = (const float*)d_in[8];
    const float* bo  = (const float*)d_in[9];
    const float* qsc = (const float*)d_in[10];
    const float* ksc = (const float*)d_in[11];
    const float* ln1 = (const float*)d_in[12];
    const float* ln2 = (const float*)d_in[13];
    const float* Wg  = (const float*)d_in[14];
    const float* W1  = (const float*)d_in[15];
    const float* W2  = (const float*)d_in[16];
    float* xres = (float*)d_out;

    char* wsb = (char*)d_ws;
    size_t off = 0;
    auto alloc = [&](size_t bytes) -> char* {
        char* p = wsb + off;
        off += (bytes + 255) & ~(size_t)255;
        return p;
    };
    const size_t WQKV = (size_t)Lc * 3 * Dc * Dc;
    const size_t WPROJ = (size_t)Lc * Dc * Hc * HSc;
    const size_t WMLP  = (size_t)Lc * Dc * HIDc;
    unsigned short* wqkvT = (unsigned short*)alloc(WQKV * 2);
    unsigned short* woT = (unsigned short*)alloc(WPROJ * 2);
    unsigned short* wgT = (unsigned short*)alloc(WMLP * 2);
    unsigned short* w1T = (unsigned short*)alloc(WMLP * 2);
    unsigned short* w2T = (unsigned short*)alloc(WMLP * 2);
    float* ropeC = (float*)alloc((size_t)Tc * 32 * 4);
    float* ropeS = (float*)alloc((size_t)Tc * 32 * 4);
    unsigned short* xln  = (unsigned short*)alloc((size_t)Bc * Tc * Dc * 2);
    unsigned short* qbuf = (unsigned short*)alloc((size_t)Bc * Tc * Hc * HSc * 2);
    unsigned short* kbuf = (unsigned short*)alloc((size_t)Bc * Tc * Hc * HSc * 2);
    unsigned short* vtg  = (unsigned short*)alloc((size_t)Bc * Hc * HSc * Tc * 2);
    unsigned short* hbuf = (unsigned short*)alloc((size_t)Bc * Tc * HIDc * 2);
    float* psum = (float*)alloc((size_t)2 * Bc * Tc * Dc * 4);   // split-K partials (2 x 16MB)

    const dim3 b32(32, 8);
    const size_t qkvStride = (size_t)3 * Dc * Dc;
    transpose_cast_kernel<<<dim3(32, 32, 4), b32, 0, stream>>>(Wq, wqkvT, 1024, 1024, qkvStride, 0);
    transpose_cast_kernel<<<dim3(32, 32, 4), b32, 0, stream>>>(Wk, wqkvT, 1024, 1024, qkvStride, 1024);
    transpose_cast_kernel<<<dim3(32, 32, 4), b32, 0, stream>>>(Wv, wqkvT, 1024, 1024, qkvStride, 2048);
    transpose_cast_kernel<<<dim3(32, 32, 4), b32, 0, stream>>>(Wo, woT, 1024, 1024, (size_t)Dc * Dc, 0);
    transpose_cast_kernel<<<dim3(128, 32, 4), b32, 0, stream>>>(Wg, wgT, 1024, 4096, (size_t)Dc * HIDc, 0);
    transpose_cast_kernel<<<dim3(128, 32, 4), b32, 0, stream>>>(W1, w1T, 1024, 4096, (size_t)Dc * HIDc, 0);
    transpose_cast_kernel<<<dim3(32, 128, 4), b32, 0, stream>>>(W2, w2T, 4096, 1024, (size_t)Dc * HIDc, 0);
    rope_table_kernel<<<128, 256, 0, stream>>>(ropeC, ropeS);

    const size_t zstr = (size_t)Bc * Tc * Dc;   // 4M elems per partial
    for (int l = 0; l < Lc; ++l) {
        const unsigned short* wqkv_l = wqkvT + (size_t)l * qkvStride;
        const unsigned short* wo_l = woT + (size_t)l * Dc * Dc;
        const unsigned short* wg_l = wgT + (size_t)l * Dc * HIDc;
        const unsigned short* w1_l = w1T + (size_t)l * Dc * HIDc;
        const unsigned short* w2_l = w2T + (size_t)l * Dc * HIDc;

        if (l == 0)
            rmsnorm_copy_kernel<<<4096, 256, 0, stream>>>(x, xres, ln1 + l * Dc, xln);
        else  // fold previous layer's split-K down-proj partials into xres, then norm
            rmsnorm_add_kernel<<<4096, 256, 0, stream>>>(xres, psum, psum + zstr, ln1 + l * Dc, xln);
        // fused QKV: M=4096, N=3072, K=1024 -> 768 blocks (3/CU); V written pre-transposed
        gemm_bt_kernel<0><<<768, 256, 0, stream>>>(
            xln, wqkv_l, bq + l * 1024, bk + l * 1024, bv + l * 1024,
            qbuf, kbuf, vtg, nullptr, nullptr, 3072, 1024, 1024, 0, 24);
        // merged q+k rope (blockIdx.y selects buffer)
        qk_rope_kernel<<<dim3(2048, 2), 256, 0, stream>>>(qbuf, kbuf, qsc + l * 64, ksc + l * 64,
                                                          ropeC, ropeS);
        // attention: QBLK=128 -> 8 q-blocks x 16 heads x 4 batch = 512 blocks x 512 thr
        attn_kernel<<<dim3(8, 16, 4), 512, 0, stream>>>(qbuf, kbuf, vtg, xln);
        // Wo: M=4096, N=1024, K=1024 full-K; residual += (with bias)
        gemm_bt_kernel<1><<<256, 256, 0, stream>>>(
            xln, wo_l, bo + l * 1024, nullptr, nullptr,
            nullptr, nullptr, nullptr, xres, xres, 1024, 1024, 1024, 0, 8);
        rmsnorm_kernel<<<4096, 256, 0, stream>>>(xres, ln2 + l * Dc, xln);
        // fused MLP gate+up (wave-specialized, 2 blocks/CU): 1024 blocks x 512 thr
        gemm_mlp_kernel<<<1024, 512, 0, stream>>>(xln, wg_l, w1_l, hbuf, 4096, 1024, 32);
        // down: M=4096, N=1024, K=4096 split-K x2 -> f32 partials (folded next layer)
        gemm_bt_kernel<4><<<dim3(256, 1, 2), 256, 0, stream>>>(
            hbuf, w2_l, nullptr, nullptr, nullptr,
            nullptr, nullptr, nullptr, nullptr, psum, 1024, 4096, 2048, zstr, 8);
    }
    // finalize last layer's residual
    reduce_res_kernel<<<4096, 256, 0, stream>>>(psum, psum + zstr, xres, (int)(zstr / 4));
}